// Round 6
// baseline (942.398 us; speedup 1.0000x reference)
//
#include <hip/hip_runtime.h>
#include <hip/hip_bf16.h>

typedef __bf16 bf16;
typedef __bf16 bf16x8 __attribute__((ext_vector_type(8)));
typedef __bf16 bf16x4 __attribute__((ext_vector_type(4)));
typedef __bf16 bf16x2 __attribute__((ext_vector_type(2)));
typedef float f32x4 __attribute__((ext_vector_type(4)));
typedef float f32x2 __attribute__((ext_vector_type(2)));

#define BATCH 32
#define N_ID 1024
#define L_IN 512

static const long ACT_E = (long)BATCH * N_ID * L_IN;   // 16,777,216
static const long S_NL  = (long)N_ID * L_IN;           // 524288
static const long S_TT  = (long)N_ID * N_ID;           // 1048576

__device__ __forceinline__ void gload16(const bf16* g, bf16* l)
{
    __builtin_amdgcn_global_load_lds((__attribute__((address_space(1))) void*)g,
                                     (__attribute__((address_space(3))) void*)l, 16, 0, 0);
}

// ---------------------------------------------------------------------------
// 128x128 BK=32 double-buffered counted 2-phase NT GEMM (4 blocks/CU).
// C[m,n] = sum_k A[m,k]*B[n,k]; strides lda/ldb/ldc decoupled (merged QK).
// LDS swizzle: 64B rows; write chunk c^((row>>1)&3) at slot c (via pre-swizzled
// global src), read slot kg^((fr>>1)&3) -> lane-octets cover all 8 bank quads.
// EPI: 0 bf16=acc+biasCol[n]; 1 bf16=acc+biasRow[m]; 2 bf16=acc*scale;
//      3 bf16=acc; 4 bf16=acc*scal2[0]+scal2[1]; 5 bf16=acc+ResBF16+biasCol[n]
// ---------------------------------------------------------------------------
#define VM0 asm volatile("s_waitcnt vmcnt(0)" ::: "memory")
#define BAR __builtin_amdgcn_s_barrier()

#define COMPUTE(BUF) \
    { \
      bf16x8 af[4], bfv[4]; \
_Pragma("unroll") \
      for (int i = 0; i < 4; ++i) \
        af[i] = *(const bf16x8*)&lds[BUF][0][(wm * 64 + i * 16 + fr) * 32 + slotk]; \
_Pragma("unroll") \
      for (int j = 0; j < 4; ++j) \
        bfv[j] = *(const bf16x8*)&lds[BUF][1][(wn * 64 + j * 16 + fr) * 32 + slotk]; \
_Pragma("unroll") \
      for (int i = 0; i < 4; ++i) \
_Pragma("unroll") \
        for (int j = 0; j < 4; ++j) \
          acc[i][j] = __builtin_amdgcn_mfma_f32_16x16x32_bf16(af[i], bfv[j], acc[i][j], 0, 0, 0); \
    }

#define STAGE(BUF, KT) { stg(BUF, 0, Ab, lda, m0, KT); stg(BUF, 1, Bb, ldb, n0, KT); }

template<int EPI>
__global__ __launch_bounds__(256, 4)
void gemm2(const bf16* __restrict__ A, const bf16* __restrict__ Bm, void* __restrict__ Cout,
           const float* __restrict__ biasCol, const float* __restrict__ biasRow,
           const void* __restrict__ Res, const float* __restrict__ scal2,
           float scale, int K,
           long lda, long ldb, long ldc,
           long sA, long sB, long sC, long sRes,
           unsigned gx, unsigned gxy, unsigned nwg)
{
    __shared__ __align__(16) bf16 lds[2][2][128 * 32];   // [buf][A/B] 8KB each

    // bijective XCD swizzle (m204)
    unsigned id = blockIdx.x;
    {
        const unsigned q = nwg >> 3, r = nwg & 7;
        const unsigned xcd = id & 7, off = id >> 3;
        id = (xcd < r ? xcd * (q + 1) : r * (q + 1) + (xcd - r) * q) + off;
    }
    const unsigned bz = id / gxy;
    const unsigned rem = id - bz * gxy;
    const unsigned by = rem / gx;
    const unsigned bx = rem - by * gx;

    const int t = threadIdx.x;
    const int w = t >> 6;
    const int lane = t & 63;
    const int fr = lane & 15;
    const int kg = lane >> 4;
    const int wm = w >> 1, wn = w & 1;
    const long z = bz;
    const long m0 = (long)bx * 128;
    const long n0 = (long)by * 128;
    const bf16* Ab = A + z * sA;
    const bf16* Bb = Bm + z * sB;

    const int srow = w * 16 + (lane >> 2);           // staging row (0..63)
    const int gc = (lane & 3) ^ ((lane >> 3) & 3);   // pre-swizzled global chunk
    const int slotk = (kg ^ ((fr >> 1) & 3)) * 8;    // read slot (conflict-free octets)

    auto stg = [&](int buf, int ab, const bf16* base, long ld, long rc0, int kt) {
#pragma unroll
        for (int r = 0; r < 2; ++r) {
            const int row = r * 64 + srow;
            const bf16* src = base + (rc0 + row) * ld + kt * 32 + gc * 8;
            gload16(src, (bf16*)&lds[buf][ab][row * 32 + (lane & 3) * 8]);
        }
    };

    f32x4 acc[4][4] = {};

    STAGE(0, 0);
    VM0; BAR;

    const int NT = K >> 5;            // K % 64 == 0 -> NT even
    for (int kt = 0; kt < NT; kt += 2) {
        if (kt + 1 < NT) STAGE(1, kt + 1);
        COMPUTE(0);
        VM0; BAR;
        if (kt + 2 < NT) STAGE(0, kt + 2);
        COMPUTE(1);
        VM0; BAR;
    }

    float e0 = 0.f, e1 = 0.f;
    if constexpr (EPI == 4) { e0 = scal2[0]; e1 = scal2[1]; }

#pragma unroll
    for (int i = 0; i < 4; ++i) {
        const long rb = m0 + wm * 64 + i * 16 + kg * 4;
#pragma unroll
        for (int j = 0; j < 4; ++j) {
            const long cc = n0 + wn * 64 + j * 16 + fr;
#pragma unroll
            for (int r = 0; r < 4; ++r) {
                const long rr = rb + r;
                const float v = acc[i][j][r];
                const long idx = z * sC + rr * ldc + cc;
                if constexpr (EPI == 0)      ((bf16*)Cout)[idx] = (bf16)(v + biasCol[cc]);
                else if constexpr (EPI == 1) ((bf16*)Cout)[idx] = (bf16)(v + biasRow[rr]);
                else if constexpr (EPI == 2) ((bf16*)Cout)[idx] = (bf16)(v * scale);
                else if constexpr (EPI == 3) ((bf16*)Cout)[idx] = (bf16)v;
                else if constexpr (EPI == 4) ((bf16*)Cout)[idx] = (bf16)(v * e0 + e1);
                else ((bf16*)Cout)[idx] = (bf16)(v + (float)((const bf16*)Res)[z * sRes + rr * ldc + cc] + biasCol[cc]);
            }
        }
    }
}

// ---------------------------------------------------------------------------
// Row softmax, bf16 in -> bf16 out, IN-PLACE (P aliases S). Scale pre-applied.
// ---------------------------------------------------------------------------
template<int W>
__global__ __launch_bounds__(256)
void softmax_rows(const bf16* __restrict__ S, bf16* __restrict__ P)
{
    constexpr int NV = W / 256;
    const long row = blockIdx.x;
    const int t = threadIdx.x;
    const bf16* src = S + row * (long)W + t * NV;
    bf16* dst = P + row * (long)W + t * NV;

    float v[NV];
    if constexpr (NV == 4) { bf16x4 x = *(const bf16x4*)src;
        v[0] = (float)x[0]; v[1] = (float)x[1]; v[2] = (float)x[2]; v[3] = (float)x[3]; }
    else { bf16x2 x = *(const bf16x2*)src; v[0] = (float)x[0]; v[1] = (float)x[1]; }

    float m = v[0];
#pragma unroll
    for (int i = 1; i < NV; ++i) m = fmaxf(m, v[i]);
#pragma unroll
    for (int o = 32; o > 0; o >>= 1) m = fmaxf(m, __shfl_xor(m, o));
    __shared__ float red[8];
    const int w = t >> 6, l = t & 63;
    if (l == 0) red[w] = m;
    __syncthreads();
    m = fmaxf(fmaxf(red[0], red[1]), fmaxf(red[2], red[3]));

    float s = 0.f;
#pragma unroll
    for (int i = 0; i < NV; ++i) { v[i] = __expf(v[i] - m); s += v[i]; }
#pragma unroll
    for (int o = 32; o > 0; o >>= 1) s += __shfl_xor(s, o);
    if (l == 0) red[4 + w] = s;
    __syncthreads();
    s = red[4] + red[5] + red[6] + red[7];
    const float inv = 1.f / s;

    if constexpr (NV == 4) {
        bf16x4 o4;
#pragma unroll
        for (int i = 0; i < 4; ++i) o4[i] = (bf16)(v[i] * inv);
        *(bf16x4*)dst = o4;
    } else {
        bf16x2 o2;
#pragma unroll
        for (int i = 0; i < 2; ++i) o2[i] = (bf16)(v[i] * inv);
        *(bf16x2*)dst = o2;
    }
}

// ---------------------------------------------------------------------------
// LayerNorm over rows of 512, bf16 in. OUTBF=1 -> bf16 out, else f32 out.
// ---------------------------------------------------------------------------
template<int OUTBF>
__global__ __launch_bounds__(128)
void ln_rows(const bf16* __restrict__ X, const float* __restrict__ g,
             const float* __restrict__ bta, void* __restrict__ out)
{
    const long row = blockIdx.x;
    const int t = threadIdx.x;
    bf16x4 b4 = *(const bf16x4*)(X + row * 512 + t * 4);
    float v[4] = { (float)b4[0], (float)b4[1], (float)b4[2], (float)b4[3] };
    float s1 = v[0] + v[1] + v[2] + v[3];
    float s2 = v[0]*v[0] + v[1]*v[1] + v[2]*v[2] + v[3]*v[3];
#pragma unroll
    for (int o = 32; o > 0; o >>= 1) { s1 += __shfl_xor(s1, o); s2 += __shfl_xor(s2, o); }
    __shared__ float r1[2], r2[2];
    const int w = t >> 6, l = t & 63;
    if (l == 0) { r1[w] = s1; r2[w] = s2; }
    __syncthreads();
    s1 = r1[0] + r1[1];
    s2 = r2[0] + r2[1];
    const float mean = s1 * (1.f / 512.f);
    const float var  = s2 * (1.f / 512.f) - mean * mean;
    const float rstd = rsqrtf(var + 1e-5f);
    const int c = t * 4;
    if constexpr (OUTBF) {
        bf16x4 o4;
#pragma unroll
        for (int k = 0; k < 4; ++k) o4[k] = (bf16)((v[k] - mean) * rstd * g[c + k] + bta[c + k]);
        *(bf16x4*)((bf16*)out + row * 512 + c) = o4;
    } else {
        f32x4 o4;
#pragma unroll
        for (int k = 0; k < 4; ++k) o4[k] = (v[k] - mean) * rstd * g[c + k] + bta[c + k];
        *(f32x4*)((float*)out + row * 512 + c) = o4;
    }
}

// ---------------------------------------------------------------------------
__global__ __launch_bounds__(256)
void transpose_cvt(const float* __restrict__ x, bf16* __restrict__ Xb, bf16* __restrict__ xt)
{
    __shared__ bf16 tile[32][33];
    const int b = blockIdx.z;
    const int n0 = blockIdx.x * 32, l0 = blockIdx.y * 32;
    const long base = (long)b * N_ID * L_IN;
    const int tx = threadIdx.x, ty = threadIdx.y;
#pragma unroll
    for (int i = ty; i < 32; i += 8) {
        const long idx = base + (long)(n0 + i) * L_IN + l0 + tx;
        const bf16 s = (bf16)x[idx];
        Xb[idx] = s;
        tile[i][tx] = s;
    }
    __syncthreads();
#pragma unroll
    for (int i = ty; i < 32; i += 8)
        xt[base + (long)(l0 + i) * N_ID + n0 + tx] = tile[tx][i];
}

struct Ptr6 { const float* s[6]; bf16* d[6]; };

__global__ void cvt_multi(Ptr6 p, int n)   // 4 elems/thread
{
    const int j = blockIdx.y;
    const int i = (blockIdx.x * 256 + threadIdx.x) * 4;
    if (i < n) {
        f32x4 v = *(const f32x4*)(p.s[j] + i);
        bf16x4 o; o[0] = (bf16)v[0]; o[1] = (bf16)v[1]; o[2] = (bf16)v[2]; o[3] = (bf16)v[3];
        *(bf16x4*)(p.d[j] + i) = o;
    }
}

__global__ void wo_sum2(const float* __restrict__ a, const float* __restrict__ b,
                        bf16* __restrict__ da, bf16* __restrict__ db)
{
    const int i = blockIdx.x * 256 + threadIdx.x; // < 262144
    const float* src = blockIdx.y ? b : a;
    bf16* dst = blockIdx.y ? db : da;
    const float* p = src + (long)i * 8;
    float s = 0.f;
#pragma unroll
    for (int h = 0; h < 8; ++h) s += p[h];
    dst[i] = (bf16)s;
}

__global__ void concat2(const float* __restrict__ a, const float* __restrict__ b,
                        float* __restrict__ out, int n)
{
    const int i = blockIdx.x * 256 + threadIdx.x;
    if (i < n) { out[i] = a[i]; out[n + i] = b[i]; }
}

__global__ void prep_scal(const float* __restrict__ W1, const float* __restrict__ b1, float* __restrict__ out)
{
    if (threadIdx.x == 0 && blockIdx.x == 0) {
        float s = 0.f;
        for (int h = 0; h < 8; ++h) s += W1[h];
        out[0] = s;
        out[1] = b1[0];
    }
}

// ---------------------------------------------------------------------------
static void launch_gemm(int epi, const bf16* A, const bf16* B, void* C,
                        const float* bc, const float* br, const void* res, const float* sc2,
                        float scale, int M, int N, int K,
                        long lda, long ldb, long ldc,
                        long sA, long sB, long sC, long sRes, int batches, hipStream_t st)
{
    const unsigned gx = M / 128, gy = N / 128;
    const unsigned gxy = gx * gy, nwg = gxy * (unsigned)batches;
    dim3 g(nwg), blk(256);
    switch (epi) {
    case 0: gemm2<0><<<g, blk, 0, st>>>(A, B, C, bc, br, res, sc2, scale, K, lda, ldb, ldc, sA, sB, sC, sRes, gx, gxy, nwg); break;
    case 1: gemm2<1><<<g, blk, 0, st>>>(A, B, C, bc, br, res, sc2, scale, K, lda, ldb, ldc, sA, sB, sC, sRes, gx, gxy, nwg); break;
    case 2: gemm2<2><<<g, blk, 0, st>>>(A, B, C, bc, br, res, sc2, scale, K, lda, ldb, ldc, sA, sB, sC, sRes, gx, gxy, nwg); break;
    case 3: gemm2<3><<<g, blk, 0, st>>>(A, B, C, bc, br, res, sc2, scale, K, lda, ldb, ldc, sA, sB, sC, sRes, gx, gxy, nwg); break;
    case 4: gemm2<4><<<g, blk, 0, st>>>(A, B, C, bc, br, res, sc2, scale, K, lda, ldb, ldc, sA, sB, sC, sRes, gx, gxy, nwg); break;
    default: gemm2<5><<<g, blk, 0, st>>>(A, B, C, bc, br, res, sc2, scale, K, lda, ldb, ldc, sA, sB, sC, sRes, gx, gxy, nwg); break;
    }
}

extern "C" void kernel_launch(void* const* d_in, const int* in_sizes, int n_in,
                              void* d_out, int out_size, void* d_ws, size_t ws_size,
                              hipStream_t stream)
{
    (void)in_sizes; (void)n_in; (void)out_size;

    const float* x   = (const float*)d_in[0];
    const float* tWq = (const float*)d_in[1];  const float* tbq = (const float*)d_in[2];
    const float* tWk = (const float*)d_in[3];  const float* tbk = (const float*)d_in[4];
    const float* tWv = (const float*)d_in[5];  const float* tbv = (const float*)d_in[6];
    const float* tWo = (const float*)d_in[7];  const float* tbo = (const float*)d_in[8];
    const float* tg  = (const float*)d_in[9];  const float* tb  = (const float*)d_in[10];
    const float* cWq = (const float*)d_in[11]; const float* cbq = (const float*)d_in[12];
    const float* cWk = (const float*)d_in[13]; const float* cbk = (const float*)d_in[14];
    const float* cWv = (const float*)d_in[15]; const float* cbv = (const float*)d_in[16];
    const float* cWo = (const float*)d_in[17]; const float* cbo = (const float*)d_in[18];
    const float* cg  = (const float*)d_in[19]; const float* cb  = (const float*)d_in[20];
    const float* sWq = (const float*)d_in[21]; const float* sbq = (const float*)d_in[22];
    const float* sWk = (const float*)d_in[23]; const float* sbk = (const float*)d_in[24];
    const float* sWv = (const float*)d_in[25]; const float* sbv = (const float*)d_in[26];
    const float* sW1 = (const float*)d_in[27]; const float* sb1 = (const float*)d_in[28];

    char* p = (char*)d_ws;
    auto alloc = [&](size_t bytes) -> char* {
        char* r = p; p += (bytes + 255) & ~(size_t)255; return r;
    };

    // merged [Wq|Wk] (row-concat) per stage; separate Wv
    bf16* WqkT = (bf16*)alloc(2 * 262144 * 2);
    bf16* WvT  = (bf16*)alloc(262144 * 2);
    bf16* WqC  = (bf16*)alloc(262144 * 2);  bf16* WkC = (bf16*)alloc(262144 * 2);  bf16* WvC = (bf16*)alloc(262144 * 2);
    bf16* WqkS = (bf16*)alloc(2 * 1048576 * 2);
    bf16* WvS  = (bf16*)alloc(1048576 * 2);
    bf16* WsT  = (bf16*)alloc(262144 * 2);  bf16* WsC = (bf16*)alloc(262144 * 2);
    float* scal = (float*)alloc(256);
    float* bqkT = (float*)alloc(1024 * 4);
    float* sbqk = (float*)alloc(2048 * 4);

    const size_t ACT_B = (size_t)ACT_E * 2;
    bf16* bufQK = (bf16*)alloc(2 * ACT_B);  // [32768,1024] or [16384,2048]; Lm -> Q half
    bf16* Xb    = (bf16*)alloc(ACT_B);      // reused as SO after stage T
    bf16* xt    = (bf16*)alloc(ACT_B);
    bf16* bufV  = (bf16*)alloc(ACT_B);
    bf16* TO    = (bf16*)alloc(ACT_B);
    bf16* PL    = (bf16*)alloc(ACT_B);      // preLN scratch

    size_t used = (size_t)(p - (char*)d_ws);
    int CB = 32;
    while (CB > 1 && used + (size_t)CB * 2097152ULL + 4096 > ws_size) CB >>= 1;
    bf16* Sbuf = (bf16*)alloc((size_t)CB * 2097152ULL);
    bf16* Pbuf = Sbuf;   // softmax in-place

    const float rsc_t = 0.08838834764831845f;  // 1/sqrt(1024/8)
    const float rsc_s = 0.125f;                // 1/sqrt(512/8)

    // ---- prep ----
    Ptr6 smallW;
    smallW.s[0] = tWq; smallW.s[1] = tWk; smallW.s[2] = tWv;
    smallW.s[3] = cWq; smallW.s[4] = cWk; smallW.s[5] = cWv;
    smallW.d[0] = WqkT; smallW.d[1] = WqkT + 262144; smallW.d[2] = WvT;
    smallW.d[3] = WqC;  smallW.d[4] = WkC;           smallW.d[5] = WvC;
    cvt_multi<<<dim3(256, 6), dim3(256), 0, stream>>>(smallW, 262144);
    Ptr6 bigW = {};
    bigW.s[0] = sWq;  bigW.s[1] = sWk;            bigW.s[2] = sWv;
    bigW.d[0] = WqkS; bigW.d[1] = WqkS + 1048576; bigW.d[2] = WvS;
    cvt_multi<<<dim3(1024, 3), dim3(256), 0, stream>>>(bigW, 1048576);
    wo_sum2<<<dim3(1024, 2), dim3(256), 0, stream>>>(tWo, cWo, WsT, WsC);
    concat2<<<dim3(2), dim3(256), 0, stream>>>(tbq, tbk, bqkT, 512);
    concat2<<<dim3(4), dim3(256), 0, stream>>>(sbq, sbk, sbqk, 1024);
    prep_scal<<<dim3(1), dim3(64), 0, stream>>>(sW1, sb1, scal);
    transpose_cvt<<<dim3(32, 16, BATCH), dim3(32, 8), 0, stream>>>(x, Xb, xt);

    // time/cross attention: QK^T*rsc -> softmax -> Lm = P@Vt^T (Lm -> Q half of bufQK)
    auto attn_tc = [&](float rsc) {
        for (int c0 = 0; c0 < BATCH; c0 += CB) {
            const long offQ = (long)c0 * S_TT;
            const long offV = (long)c0 * S_NL;
            launch_gemm(2, bufQK + offQ, bufQK + 512 + offQ, Sbuf, nullptr, nullptr, nullptr, nullptr, rsc,
                        1024, 1024, 512, 1024, 1024, 1024, S_TT, S_TT, S_TT, 0, CB, stream);
            softmax_rows<1024><<<dim3(CB * 1024), dim3(256), 0, stream>>>(Sbuf, Pbuf);
            // Lm[n,l] = sum_j P[n,j] * Vt[l,j]; Vt stored [512,1024] -> ldb = 1024
            launch_gemm(3, Pbuf, bufV + offV, bufQK + offQ, nullptr, nullptr, nullptr, nullptr, 0.f,
                        1024, 512, 1024, 1024, 1024, 1024, S_TT, S_NL, S_TT, 0, CB, stream);
        }
    };

    // ==== Stage T (time de_att) ====
    launch_gemm(0, Xb, WqkT, bufQK, bqkT, nullptr, nullptr, nullptr, 0.f,
                32768, 1024, 512, 512, 512, 1024, 0, 0, 0, 0, 1, stream);
    launch_gemm(1, WvT, Xb, bufV, nullptr, tbv, nullptr, nullptr, 0.f,
                512, 1024, 512, 512, 512, 1024, 0, S_NL, S_NL, 0, BATCH, stream);
    attn_tc(rsc_t);
    launch_gemm(5, bufQK, WsT, PL, tbo, nullptr, Xb, nullptr, 0.f,
                32768, 512, 512, 1024, 512, 512, 0, 0, 0, 0, 1, stream);
    ln_rows<1><<<dim3(32768), dim3(128), 0, stream>>>(PL, tg, tb, TO);

    // ==== Stage S (space attention) ====
    bf16* SOp = Xb;   // Xb dead after stage T -> space_out
    launch_gemm(0, xt, WqkS, bufQK, sbqk, nullptr, nullptr, nullptr, 0.f,
                16384, 2048, 1024, 1024, 1024, 2048, 0, 0, 0, 0, 1, stream);
    launch_gemm(1, WvS, xt, bufV, nullptr, sbv, nullptr, nullptr, 0.f,
                1024, 512, 1024, 1024, 1024, 512, 0, S_NL, S_NL, 0, BATCH, stream);
    for (int c0 = 0; c0 < BATCH; c0 += CB) {
        const long offQ = (long)c0 * S_TT;       // 512*2048 = S_TT per batch
        const long offV = (long)c0 * S_NL;
        launch_gemm(2, bufQK + offQ, bufQK + 1024 + offQ, Sbuf, nullptr, nullptr, nullptr, nullptr, rsc_s,
                    512, 512, 1024, 2048, 2048, 512, S_TT, S_TT, (long)L_IN * L_IN, 0, CB, stream);
        softmax_rows<512><<<dim3(CB * 512), dim3(256), 0, stream>>>(Sbuf, Pbuf);
        launch_gemm(4, bufV + offV, Pbuf, SOp + offV, nullptr, nullptr, nullptr, scal, 0.f,
                    1024, 512, 512, 512, 512, 512, S_NL, (long)L_IN * L_IN, S_NL, 0, CB, stream);
    }

    // ==== Stage C (cross de_att) ====
    launch_gemm(0, SOp, WqC, bufQK, cbq, nullptr, nullptr, nullptr, 0.f,
                32768, 512, 512, 512, 512, 1024, 0, 0, 0, 0, 1, stream);
    launch_gemm(0, TO, WkC, bufQK + 512, cbk, nullptr, nullptr, nullptr, 0.f,
                32768, 512, 512, 512, 512, 1024, 0, 0, 0, 0, 1, stream);
    launch_gemm(1, WvC, TO, bufV, nullptr, cbv, nullptr, nullptr, 0.f,
                512, 1024, 512, 512, 512, 1024, 0, S_NL, S_NL, 0, BATCH, stream);
    attn_tc(rsc_t);
    launch_gemm(5, bufQK, WsC, PL, cbo, nullptr, TO, nullptr, 0.f,
                32768, 512, 512, 1024, 512, 512, 0, 0, 0, 0, 1, stream);
    ln_rows<0><<<dim3(32768), dim3(128), 0, stream>>>(PL, cg, cb, d_out);
}

// Round 7
// 912.650 us; speedup vs baseline: 1.0326x; 1.0326x over previous
//
#include <hip/hip_runtime.h>
#include <hip/hip_bf16.h>

typedef __bf16 bf16;
typedef __bf16 bf16x8 __attribute__((ext_vector_type(8)));
typedef __bf16 bf16x4 __attribute__((ext_vector_type(4)));
typedef __bf16 bf16x2 __attribute__((ext_vector_type(2)));
typedef float f32x4 __attribute__((ext_vector_type(4)));
typedef float f32x2 __attribute__((ext_vector_type(2)));

#define BATCH 32
#define N_ID 1024
#define L_IN 512

static const long ACT_E = (long)BATCH * N_ID * L_IN;   // 16,777,216
static const long S_NL  = (long)N_ID * L_IN;           // 524288
static const long S_TT  = (long)N_ID * N_ID;           // 1048576

__device__ __forceinline__ void gload16(const bf16* g, bf16* l)
{
    __builtin_amdgcn_global_load_lds((__attribute__((address_space(1))) void*)g,
                                     (__attribute__((address_space(3))) void*)l, 16, 0, 0);
}

// ---------------------------------------------------------------------------
// 128x128 BK=32 double-buffered counted 2-phase NT GEMM (4 blocks/CU).
// C[m,n] = sum_k A[m,k]*B[n,k]; strides lda/ldb/ldc decoupled.
// Grid decode: N-tile fastest -> concurrent blocks on an XCD share the A-panel
// (A fetched ~once per dispatch; B is L2-resident weights/panels).
// LDS swizzle: write chunk c^((row>>1)&3) at slot c (pre-swizzled global src),
// read slot kg^((fr>>1)&3) -> lane-octets cover all 8 bank quads (2-way max).
// EPI: 0 bf16=acc+biasCol[n]; 1 bf16=acc+biasRow[m]; 2 bf16=acc*scale;
//      3 bf16=acc; 4 bf16=acc*scal2[0]+scal2[1]; 5 bf16=acc+ResBF16+biasCol[n]
// ---------------------------------------------------------------------------
#define VM0 asm volatile("s_waitcnt vmcnt(0)" ::: "memory")
#define BAR __builtin_amdgcn_s_barrier()

#define COMPUTE(BUF) \
    { \
      bf16x8 af[4], bfv[4]; \
_Pragma("unroll") \
      for (int i = 0; i < 4; ++i) \
        af[i] = *(const bf16x8*)&lds[BUF][0][(wm * 64 + i * 16 + fr) * 32 + slotk]; \
_Pragma("unroll") \
      for (int j = 0; j < 4; ++j) \
        bfv[j] = *(const bf16x8*)&lds[BUF][1][(wn * 64 + j * 16 + fr) * 32 + slotk]; \
_Pragma("unroll") \
      for (int i = 0; i < 4; ++i) \
_Pragma("unroll") \
        for (int j = 0; j < 4; ++j) \
          acc[i][j] = __builtin_amdgcn_mfma_f32_16x16x32_bf16(af[i], bfv[j], acc[i][j], 0, 0, 0); \
    }

#define STAGE(BUF, KT) { stg(BUF, 0, Ab, lda, m0, KT); stg(BUF, 1, Bb, ldb, n0, KT); }

template<int EPI>
__global__ __launch_bounds__(256, 4)
void gemm2(const bf16* __restrict__ A, const bf16* __restrict__ Bm, void* __restrict__ Cout,
           const float* __restrict__ biasCol, const float* __restrict__ biasRow,
           const void* __restrict__ Res, const float* __restrict__ scal2,
           float scale, int K,
           long lda, long ldb, long ldc,
           long sA, long sB, long sC, long sRes,
           unsigned gy, unsigned gxy, unsigned nwg)
{
    __shared__ __align__(16) bf16 lds[2][2][128 * 32];   // [buf][A/B] 8KB each

    // bijective XCD swizzle (m204): each XCD owns a contiguous id chunk.
    unsigned id = blockIdx.x;
    {
        const unsigned q = nwg >> 3, r = nwg & 7;
        const unsigned xcd = id & 7, off = id >> 3;
        id = (xcd < r ? xcd * (q + 1) : r * (q + 1) + (xcd - r) * q) + off;
    }
    const unsigned bz = id / gxy;
    const unsigned rem = id - bz * gxy;
    const unsigned bx = rem / gy;        // M-tile (A-panel): slow-varying
    const unsigned by = rem - bx * gy;   // N-tile: fastest -> A-panel reuse in L2

    const int t = threadIdx.x;
    const int w = t >> 6;
    const int lane = t & 63;
    const int fr = lane & 15;
    const int kg = lane >> 4;
    const int wm = w >> 1, wn = w & 1;
    const long z = bz;
    const long m0 = (long)bx * 128;
    const long n0 = (long)by * 128;
    const bf16* Ab = A + z * sA;
    const bf16* Bb = Bm + z * sB;

    const int srow = w * 16 + (lane >> 2);           // staging row (0..63)
    const int gc = (lane & 3) ^ ((lane >> 3) & 3);   // pre-swizzled global chunk
    const int slotk = (kg ^ ((fr >> 1) & 3)) * 8;    // read slot (conflict-free octets)

    auto stg = [&](int buf, int ab, const bf16* base, long ld, long rc0, int kt) {
#pragma unroll
        for (int r = 0; r < 2; ++r) {
            const int row = r * 64 + srow;
            const bf16* src = base + (rc0 + row) * ld + kt * 32 + gc * 8;
            gload16(src, (bf16*)&lds[buf][ab][row * 32 + (lane & 3) * 8]);
        }
    };

    f32x4 acc[4][4] = {};

    STAGE(0, 0);
    VM0; BAR;

    const int NT = K >> 5;            // K % 64 == 0 -> NT even
    for (int kt = 0; kt < NT; kt += 2) {
        if (kt + 1 < NT) STAGE(1, kt + 1);
        COMPUTE(0);
        VM0; BAR;
        if (kt + 2 < NT) STAGE(0, kt + 2);
        COMPUTE(1);
        VM0; BAR;
    }

    float e0 = 0.f, e1 = 0.f;
    if constexpr (EPI == 4) { e0 = scal2[0]; e1 = scal2[1]; }

#pragma unroll
    for (int i = 0; i < 4; ++i) {
        const long rb = m0 + wm * 64 + i * 16 + kg * 4;
#pragma unroll
        for (int j = 0; j < 4; ++j) {
            const long cc = n0 + wn * 64 + j * 16 + fr;
#pragma unroll
            for (int r = 0; r < 4; ++r) {
                const long rr = rb + r;
                const float v = acc[i][j][r];
                const long idx = z * sC + rr * ldc + cc;
                if constexpr (EPI == 0)      ((bf16*)Cout)[idx] = (bf16)(v + biasCol[cc]);
                else if constexpr (EPI == 1) ((bf16*)Cout)[idx] = (bf16)(v + biasRow[rr]);
                else if constexpr (EPI == 2) ((bf16*)Cout)[idx] = (bf16)(v * scale);
                else if constexpr (EPI == 3) ((bf16*)Cout)[idx] = (bf16)v;
                else if constexpr (EPI == 4) ((bf16*)Cout)[idx] = (bf16)(v * e0 + e1);
                else ((bf16*)Cout)[idx] = (bf16)(v + (float)((const bf16*)Res)[z * sRes + rr * ldc + cc] + biasCol[cc]);
            }
        }
    }
}

// ---------------------------------------------------------------------------
// Row softmax, bf16 in -> bf16 out, IN-PLACE (P aliases S). Scale pre-applied.
// ---------------------------------------------------------------------------
template<int W>
__global__ __launch_bounds__(256)
void softmax_rows(const bf16* __restrict__ S, bf16* __restrict__ P)
{
    constexpr int NV = W / 256;
    const long row = blockIdx.x;
    const int t = threadIdx.x;
    const bf16* src = S + row * (long)W + t * NV;
    bf16* dst = P + row * (long)W + t * NV;

    float v[NV];
    if constexpr (NV == 4) { bf16x4 x = *(const bf16x4*)src;
        v[0] = (float)x[0]; v[1] = (float)x[1]; v[2] = (float)x[2]; v[3] = (float)x[3]; }
    else { bf16x2 x = *(const bf16x2*)src; v[0] = (float)x[0]; v[1] = (float)x[1]; }

    float m = v[0];
#pragma unroll
    for (int i = 1; i < NV; ++i) m = fmaxf(m, v[i]);
#pragma unroll
    for (int o = 32; o > 0; o >>= 1) m = fmaxf(m, __shfl_xor(m, o));
    __shared__ float red[8];
    const int w = t >> 6, l = t & 63;
    if (l == 0) red[w] = m;
    __syncthreads();
    m = fmaxf(fmaxf(red[0], red[1]), fmaxf(red[2], red[3]));

    float s = 0.f;
#pragma unroll
    for (int i = 0; i < NV; ++i) { v[i] = __expf(v[i] - m); s += v[i]; }
#pragma unroll
    for (int o = 32; o > 0; o >>= 1) s += __shfl_xor(s, o);
    if (l == 0) red[4 + w] = s;
    __syncthreads();
    s = red[4] + red[5] + red[6] + red[7];
    const float inv = 1.f / s;

    if constexpr (NV == 4) {
        bf16x4 o4;
#pragma unroll
        for (int i = 0; i < 4; ++i) o4[i] = (bf16)(v[i] * inv);
        *(bf16x4*)dst = o4;
    } else {
        bf16x2 o2;
#pragma unroll
        for (int i = 0; i < 2; ++i) o2[i] = (bf16)(v[i] * inv);
        *(bf16x2*)dst = o2;
    }
}

// ---------------------------------------------------------------------------
// LayerNorm over rows of 512, bf16 in. OUTBF=1 -> bf16 out, else f32 out.
// ---------------------------------------------------------------------------
template<int OUTBF>
__global__ __launch_bounds__(128)
void ln_rows(const bf16* __restrict__ X, const float* __restrict__ g,
             const float* __restrict__ bta, void* __restrict__ out)
{
    const long row = blockIdx.x;
    const int t = threadIdx.x;
    bf16x4 b4 = *(const bf16x4*)(X + row * 512 + t * 4);
    float v[4] = { (float)b4[0], (float)b4[1], (float)b4[2], (float)b4[3] };
    float s1 = v[0] + v[1] + v[2] + v[3];
    float s2 = v[0]*v[0] + v[1]*v[1] + v[2]*v[2] + v[3]*v[3];
#pragma unroll
    for (int o = 32; o > 0; o >>= 1) { s1 += __shfl_xor(s1, o); s2 += __shfl_xor(s2, o); }
    __shared__ float r1[2], r2[2];
    const int w = t >> 6, l = t & 63;
    if (l == 0) { r1[w] = s1; r2[w] = s2; }
    __syncthreads();
    s1 = r1[0] + r1[1];
    s2 = r2[0] + r2[1];
    const float mean = s1 * (1.f / 512.f);
    const float var  = s2 * (1.f / 512.f) - mean * mean;
    const float rstd = rsqrtf(var + 1e-5f);
    const int c = t * 4;
    if constexpr (OUTBF) {
        bf16x4 o4;
#pragma unroll
        for (int k = 0; k < 4; ++k) o4[k] = (bf16)((v[k] - mean) * rstd * g[c + k] + bta[c + k]);
        *(bf16x4*)((bf16*)out + row * 512 + c) = o4;
    } else {
        f32x4 o4;
#pragma unroll
        for (int k = 0; k < 4; ++k) o4[k] = (v[k] - mean) * rstd * g[c + k] + bta[c + k];
        *(f32x4*)((float*)out + row * 512 + c) = o4;
    }
}

// ---------------------------------------------------------------------------
__global__ __launch_bounds__(256)
void transpose_cvt(const float* __restrict__ x, bf16* __restrict__ Xb, bf16* __restrict__ xt)
{
    __shared__ bf16 tile[32][33];
    const int b = blockIdx.z;
    const int n0 = blockIdx.x * 32, l0 = blockIdx.y * 32;
    const long base = (long)b * N_ID * L_IN;
    const int tx = threadIdx.x, ty = threadIdx.y;
#pragma unroll
    for (int i = ty; i < 32; i += 8) {
        const long idx = base + (long)(n0 + i) * L_IN + l0 + tx;
        const bf16 s = (bf16)x[idx];
        Xb[idx] = s;
        tile[i][tx] = s;
    }
    __syncthreads();
#pragma unroll
    for (int i = ty; i < 32; i += 8)
        xt[base + (long)(l0 + i) * N_ID + n0 + tx] = tile[tx][i];
}

struct Ptr6 { const float* s[6]; bf16* d[6]; };

__global__ void cvt_multi(Ptr6 p, int n)   // 4 elems/thread
{
    const int j = blockIdx.y;
    const int i = (blockIdx.x * 256 + threadIdx.x) * 4;
    if (i < n) {
        f32x4 v = *(const f32x4*)(p.s[j] + i);
        bf16x4 o; o[0] = (bf16)v[0]; o[1] = (bf16)v[1]; o[2] = (bf16)v[2]; o[3] = (bf16)v[3];
        *(bf16x4*)(p.d[j] + i) = o;
    }
}

__global__ void wo_sum2(const float* __restrict__ a, const float* __restrict__ b,
                        bf16* __restrict__ da, bf16* __restrict__ db)
{
    const int i = blockIdx.x * 256 + threadIdx.x; // < 262144
    const float* src = blockIdx.y ? b : a;
    bf16* dst = blockIdx.y ? db : da;
    const float* p = src + (long)i * 8;
    float s = 0.f;
#pragma unroll
    for (int h = 0; h < 8; ++h) s += p[h];
    dst[i] = (bf16)s;
}

__global__ void concat2(const float* __restrict__ a, const float* __restrict__ b,
                        float* __restrict__ out, int n)
{
    const int i = blockIdx.x * 256 + threadIdx.x;
    if (i < n) { out[i] = a[i]; out[n + i] = b[i]; }
}

__global__ void prep_scal(const float* __restrict__ W1, const float* __restrict__ b1, float* __restrict__ out)
{
    if (threadIdx.x == 0 && blockIdx.x == 0) {
        float s = 0.f;
        for (int h = 0; h < 8; ++h) s += W1[h];
        out[0] = s;
        out[1] = b1[0];
    }
}

// ---------------------------------------------------------------------------
static void launch_gemm(int epi, const bf16* A, const bf16* B, void* C,
                        const float* bc, const float* br, const void* res, const float* sc2,
                        float scale, int M, int N, int K,
                        long lda, long ldb, long ldc,
                        long sA, long sB, long sC, long sRes, int batches, hipStream_t st)
{
    const unsigned gx = M / 128, gy = N / 128;
    const unsigned gxy = gx * gy, nwg = gxy * (unsigned)batches;
    dim3 g(nwg), blk(256);
    switch (epi) {
    case 0: gemm2<0><<<g, blk, 0, st>>>(A, B, C, bc, br, res, sc2, scale, K, lda, ldb, ldc, sA, sB, sC, sRes, gy, gxy, nwg); break;
    case 1: gemm2<1><<<g, blk, 0, st>>>(A, B, C, bc, br, res, sc2, scale, K, lda, ldb, ldc, sA, sB, sC, sRes, gy, gxy, nwg); break;
    case 2: gemm2<2><<<g, blk, 0, st>>>(A, B, C, bc, br, res, sc2, scale, K, lda, ldb, ldc, sA, sB, sC, sRes, gy, gxy, nwg); break;
    case 3: gemm2<3><<<g, blk, 0, st>>>(A, B, C, bc, br, res, sc2, scale, K, lda, ldb, ldc, sA, sB, sC, sRes, gy, gxy, nwg); break;
    case 4: gemm2<4><<<g, blk, 0, st>>>(A, B, C, bc, br, res, sc2, scale, K, lda, ldb, ldc, sA, sB, sC, sRes, gy, gxy, nwg); break;
    default: gemm2<5><<<g, blk, 0, st>>>(A, B, C, bc, br, res, sc2, scale, K, lda, ldb, ldc, sA, sB, sC, sRes, gy, gxy, nwg); break;
    }
}

extern "C" void kernel_launch(void* const* d_in, const int* in_sizes, int n_in,
                              void* d_out, int out_size, void* d_ws, size_t ws_size,
                              hipStream_t stream)
{
    (void)in_sizes; (void)n_in; (void)out_size;

    const float* x   = (const float*)d_in[0];
    const float* tWq = (const float*)d_in[1];  const float* tbq = (const float*)d_in[2];
    const float* tWk = (const float*)d_in[3];  const float* tbk = (const float*)d_in[4];
    const float* tWv = (const float*)d_in[5];  const float* tbv = (const float*)d_in[6];
    const float* tWo = (const float*)d_in[7];  const float* tbo = (const float*)d_in[8];
    const float* tg  = (const float*)d_in[9];  const float* tb  = (const float*)d_in[10];
    const float* cWq = (const float*)d_in[11]; const float* cbq = (const float*)d_in[12];
    const float* cWk = (const float*)d_in[13]; const float* cbk = (const float*)d_in[14];
    const float* cWv = (const float*)d_in[15]; const float* cbv = (const float*)d_in[16];
    const float* cWo = (const float*)d_in[17]; const float* cbo = (const float*)d_in[18];
    const float* cg  = (const float*)d_in[19]; const float* cb  = (const float*)d_in[20];
    const float* sWq = (const float*)d_in[21]; const float* sbq = (const float*)d_in[22];
    const float* sWk = (const float*)d_in[23]; const float* sbk = (const float*)d_in[24];
    const float* sWv = (const float*)d_in[25]; const float* sbv = (const float*)d_in[26];
    const float* sW1 = (const float*)d_in[27]; const float* sb1 = (const float*)d_in[28];

    char* p = (char*)d_ws;
    auto alloc = [&](size_t bytes) -> char* {
        char* r = p; p += (bytes + 255) & ~(size_t)255; return r;
    };

    // merged [Wq|Wk] (row-concat) per stage; separate Wv
    bf16* WqkT = (bf16*)alloc(2 * 262144 * 2);
    bf16* WvT  = (bf16*)alloc(262144 * 2);
    bf16* WqC  = (bf16*)alloc(262144 * 2);  bf16* WkC = (bf16*)alloc(262144 * 2);  bf16* WvC = (bf16*)alloc(262144 * 2);
    bf16* WqkS = (bf16*)alloc(2 * 1048576 * 2);
    bf16* WvS  = (bf16*)alloc(1048576 * 2);
    bf16* WsT  = (bf16*)alloc(262144 * 2);  bf16* WsC = (bf16*)alloc(262144 * 2);
    float* scal = (float*)alloc(256);
    float* bqkT = (float*)alloc(1024 * 4);
    float* sbqk = (float*)alloc(2048 * 4);

    const size_t ACT_B = (size_t)ACT_E * 2;
    bf16* bufQK = (bf16*)alloc(2 * ACT_B);  // [32768,1024] or [16384,2048]; Lm -> Q half
    bf16* Xb    = (bf16*)alloc(ACT_B);      // reused as SO after stage T
    bf16* xt    = (bf16*)alloc(ACT_B);
    bf16* bufV  = (bf16*)alloc(ACT_B);
    bf16* TO    = (bf16*)alloc(ACT_B);
    bf16* PL    = (bf16*)alloc(ACT_B);      // preLN scratch

    size_t used = (size_t)(p - (char*)d_ws);
    int CB = 32;
    while (CB > 1 && used + (size_t)CB * 2097152ULL + 4096 > ws_size) CB >>= 1;
    bf16* Sbuf = (bf16*)alloc((size_t)CB * 2097152ULL);
    bf16* Pbuf = Sbuf;   // softmax in-place

    const float rsc_t = 0.08838834764831845f;  // 1/sqrt(1024/8)
    const float rsc_s = 0.125f;                // 1/sqrt(512/8)

    // ---- prep ----
    Ptr6 smallW;
    smallW.s[0] = tWq; smallW.s[1] = tWk; smallW.s[2] = tWv;
    smallW.s[3] = cWq; smallW.s[4] = cWk; smallW.s[5] = cWv;
    smallW.d[0] = WqkT; smallW.d[1] = WqkT + 262144; smallW.d[2] = WvT;
    smallW.d[3] = WqC;  smallW.d[4] = WkC;           smallW.d[5] = WvC;
    cvt_multi<<<dim3(256, 6), dim3(256), 0, stream>>>(smallW, 262144);
    Ptr6 bigW = {};
    bigW.s[0] = sWq;  bigW.s[1] = sWk;            bigW.s[2] = sWv;
    bigW.d[0] = WqkS; bigW.d[1] = WqkS + 1048576; bigW.d[2] = WvS;
    cvt_multi<<<dim3(1024, 3), dim3(256), 0, stream>>>(bigW, 1048576);
    wo_sum2<<<dim3(1024, 2), dim3(256), 0, stream>>>(tWo, cWo, WsT, WsC);
    concat2<<<dim3(2), dim3(256), 0, stream>>>(tbq, tbk, bqkT, 512);
    concat2<<<dim3(4), dim3(256), 0, stream>>>(sbq, sbk, sbqk, 1024);
    prep_scal<<<dim3(1), dim3(64), 0, stream>>>(sW1, sb1, scal);
    transpose_cvt<<<dim3(32, 16, BATCH), dim3(32, 8), 0, stream>>>(x, Xb, xt);

    // time/cross attention: QK^T*rsc -> softmax -> Lm = P@Vt^T (Lm -> Q half of bufQK)
    auto attn_tc = [&](float rsc) {
        for (int c0 = 0; c0 < BATCH; c0 += CB) {
            const long offQ = (long)c0 * S_TT;
            const long offV = (long)c0 * S_NL;
            launch_gemm(2, bufQK + offQ, bufQK + 512 + offQ, Sbuf, nullptr, nullptr, nullptr, nullptr, rsc,
                        1024, 1024, 512, 1024, 1024, 1024, S_TT, S_TT, S_TT, 0, CB, stream);
            softmax_rows<1024><<<dim3(CB * 1024), dim3(256), 0, stream>>>(Sbuf, Pbuf);
            // Lm[n,l] = sum_j P[n,j] * Vt[l,j]; Vt stored [512,1024] -> ldb = 1024
            launch_gemm(3, Pbuf, bufV + offV, bufQK + offQ, nullptr, nullptr, nullptr, nullptr, 0.f,
                        1024, 512, 1024, 1024, 1024, 1024, S_TT, S_NL, S_TT, 0, CB, stream);
        }
    };

    // ==== Stage T (time de_att) ====
    launch_gemm(0, Xb, WqkT, bufQK, bqkT, nullptr, nullptr, nullptr, 0.f,
                32768, 1024, 512, 512, 512, 1024, 0, 0, 0, 0, 1, stream);
    launch_gemm(1, WvT, Xb, bufV, nullptr, tbv, nullptr, nullptr, 0.f,
                512, 1024, 512, 512, 512, 1024, 0, S_NL, S_NL, 0, BATCH, stream);
    attn_tc(rsc_t);
    launch_gemm(5, bufQK, WsT, PL, tbo, nullptr, Xb, nullptr, 0.f,
                32768, 512, 512, 1024, 512, 512, 0, 0, 0, 0, 1, stream);
    ln_rows<1><<<dim3(32768), dim3(128), 0, stream>>>(PL, tg, tb, TO);

    // ==== Stage S (space attention) ====
    bf16* SOp = Xb;   // Xb dead after stage T -> space_out
    launch_gemm(0, xt, WqkS, bufQK, sbqk, nullptr, nullptr, nullptr, 0.f,
                16384, 2048, 1024, 1024, 1024, 2048, 0, 0, 0, 0, 1, stream);
    launch_gemm(1, WvS, xt, bufV, nullptr, sbv, nullptr, nullptr, 0.f,
                1024, 512, 1024, 1024, 1024, 512, 0, S_NL, S_NL, 0, BATCH, stream);
    for (int c0 = 0; c0 < BATCH; c0 += CB) {
        const long offQ = (long)c0 * S_TT;       // 512*2048 = S_TT per batch
        const long offV = (long)c0 * S_NL;
        launch_gemm(2, bufQK + offQ, bufQK + 1024 + offQ, Sbuf, nullptr, nullptr, nullptr, nullptr, rsc_s,
                    512, 512, 1024, 2048, 2048, 512, S_TT, S_TT, (long)L_IN * L_IN, 0, CB, stream);
        softmax_rows<512><<<dim3(CB * 512), dim3(256), 0, stream>>>(Sbuf, Pbuf);
        launch_gemm(4, bufV + offV, Pbuf, SOp + offV, nullptr, nullptr, nullptr, scal, 0.f,
                    1024, 512, 512, 512, 512, 512, S_NL, (long)L_IN * L_IN, S_NL, 0, CB, stream);
    }

    // ==== Stage C (cross de_att) ====
    launch_gemm(0, SOp, WqC, bufQK, cbq, nullptr, nullptr, nullptr, 0.f,
                32768, 512, 512, 512, 512, 1024, 0, 0, 0, 0, 1, stream);
    launch_gemm(0, TO, WkC, bufQK + 512, cbk, nullptr, nullptr, nullptr, 0.f,
                32768, 512, 512, 512, 512, 1024, 0, 0, 0, 0, 1, stream);
    launch_gemm(1, WvC, TO, bufV, nullptr, cbv, nullptr, nullptr, 0.f,
                512, 1024, 512, 512, 512, 1024, 0, S_NL, S_NL, 0, BATCH, stream);
    attn_tc(rsc_t);
    launch_gemm(5, bufQK, WsC, PL, cbo, nullptr, TO, nullptr, 0.f,
                32768, 512, 512, 1024, 512, 512, 0, 0, 0, 0, 1, stream);
    ln_rows<0><<<dim3(32768), dim3(128), 0, stream>>>(PL, cg, cb, d_out);
}

// Round 8
// 876.086 us; speedup vs baseline: 1.0757x; 1.0417x over previous
//
#include <hip/hip_runtime.h>
#include <hip/hip_bf16.h>

typedef __bf16 bf16;
typedef __bf16 bf16x8 __attribute__((ext_vector_type(8)));
typedef __bf16 bf16x4 __attribute__((ext_vector_type(4)));
typedef __bf16 bf16x2 __attribute__((ext_vector_type(2)));
typedef float f32x4 __attribute__((ext_vector_type(4)));
typedef float f32x2 __attribute__((ext_vector_type(2)));

#define BATCH 32
#define N_ID 1024
#define L_IN 512

static const long ACT_E = (long)BATCH * N_ID * L_IN;   // 16,777,216
static const long S_NL  = (long)N_ID * L_IN;           // 524288
static const long S_TT  = (long)N_ID * N_ID;           // 1048576

__device__ __forceinline__ void gload16(const bf16* g, bf16* l)
{
    __builtin_amdgcn_global_load_lds((__attribute__((address_space(1))) void*)g,
                                     (__attribute__((address_space(3))) void*)l, 16, 0, 0);
}

// ---------------------------------------------------------------------------
// 128x128 BK=32 TRIPLE-buffered counted-vmcnt NT GEMM (T4), 3 blocks/CU.
// C[m,n] = sum_k A[m,k]*B[n,k]; strides lda/ldb/ldc decoupled.
// Pipeline: prefetch depth 3 (12 loads/wave in flight); per tile:
//   vmcnt(8) [retire ONLY the tile about to be consumed] -> barrier ->
//   ds_read + MFMA (setprio 1) -> barrier -> refill freed buffer.
// Epilogue peels 2 tiles with vmcnt(4)/vmcnt(0).
// Grid decode: N-tile fastest (A-panel L2 reuse); bijective XCD swizzle.
// LDS swizzle: write chunk c^((row>>1)&3) at slot c (pre-swizzled global src),
// read slot kg^((fr>>1)&3) -> conflict-free (2-way max).
// EPI: 0 bf16=acc+biasCol[n]; 1 bf16=acc+biasRow[m]; 2 bf16=acc*scale;
//      3 bf16=acc; 4 bf16=acc*scal2[0]+scal2[1]; 5 bf16=acc+ResBF16+biasCol[n]
// ---------------------------------------------------------------------------
#define VM8 asm volatile("s_waitcnt vmcnt(8)" ::: "memory")
#define VM4 asm volatile("s_waitcnt vmcnt(4)" ::: "memory")
#define VM0 asm volatile("s_waitcnt vmcnt(0)" ::: "memory")
#define BAR __builtin_amdgcn_s_barrier()

#define COMPUTE(CIDX) \
    { \
      const bf16* pa = ldsb + (CIDX) * 8192; \
      const bf16* pb = pa + 4096; \
      bf16x8 af[4], bfv[4]; \
_Pragma("unroll") \
      for (int i = 0; i < 4; ++i) \
        af[i] = *(const bf16x8*)(pa + (wm * 64 + i * 16 + fr) * 32 + slotk); \
_Pragma("unroll") \
      for (int j = 0; j < 4; ++j) \
        bfv[j] = *(const bf16x8*)(pb + (wn * 64 + j * 16 + fr) * 32 + slotk); \
      __builtin_amdgcn_s_setprio(1); \
_Pragma("unroll") \
      for (int i = 0; i < 4; ++i) \
_Pragma("unroll") \
        for (int j = 0; j < 4; ++j) \
          acc[i][j] = __builtin_amdgcn_mfma_f32_16x16x32_bf16(af[i], bfv[j], acc[i][j], 0, 0, 0); \
      __builtin_amdgcn_s_setprio(0); \
    }

#define STAGE(CIDX, KT) { stg(ldsb + (CIDX) * 8192, Ab, lda, m0, KT); \
                          stg(ldsb + (CIDX) * 8192 + 4096, Bb, ldb, n0, KT); }

template<int EPI>
__global__ __launch_bounds__(256, 3)
void gemm3(const bf16* __restrict__ A, const bf16* __restrict__ Bm, void* __restrict__ Cout,
           const float* __restrict__ biasCol, const float* __restrict__ biasRow,
           const void* __restrict__ Res, const float* __restrict__ scal2,
           float scale, int K,
           long lda, long ldb, long ldc,
           long sA, long sB, long sC, long sRes,
           unsigned gy, unsigned gxy, unsigned nwg)
{
    __shared__ __align__(16) bf16 ldsbuf[3 * 2 * 4096];   // 48 KB: 3 bufs x (A 8KB + B 8KB)
    bf16* ldsb = ldsbuf;

    // bijective XCD swizzle (m204)
    unsigned id = blockIdx.x;
    {
        const unsigned q = nwg >> 3, r = nwg & 7;
        const unsigned xcd = id & 7, off = id >> 3;
        id = (xcd < r ? xcd * (q + 1) : r * (q + 1) + (xcd - r) * q) + off;
    }
    const unsigned bz = id / gxy;
    const unsigned rem = id - bz * gxy;
    const unsigned bx = rem / gy;        // M-tile: slow (A-panel reuse)
    const unsigned by = rem - bx * gy;   // N-tile: fastest

    const int t = threadIdx.x;
    const int w = t >> 6;
    const int lane = t & 63;
    const int fr = lane & 15;
    const int kg = lane >> 4;
    const int wm = w >> 1, wn = w & 1;
    const long z = bz;
    const long m0 = (long)bx * 128;
    const long n0 = (long)by * 128;
    const bf16* Ab = A + z * sA;
    const bf16* Bb = Bm + z * sB;

    const int srow = w * 16 + (lane >> 2);           // staging row (0..63)
    const int gc = (lane & 3) ^ ((lane >> 3) & 3);   // pre-swizzled global chunk
    const int slotk = (kg ^ ((fr >> 1) & 3)) * 8;    // read slot (conflict-free)

    auto stg = [&](bf16* dst, const bf16* base, long ld, long rc0, int kt) {
#pragma unroll
        for (int r = 0; r < 2; ++r) {
            const int row = r * 64 + srow;
            const bf16* src = base + (rc0 + row) * ld + kt * 32 + gc * 8;
            gload16(src, dst + row * 32 + (lane & 3) * 8);
        }
    };

    f32x4 acc[4][4] = {};

    const int NT = K >> 5;     // >= 16 for all shapes here
    STAGE(0, 0); STAGE(1, 1); STAGE(2, 2);   // 12 loads/wave in flight

    int c = 0;
    for (int kt = 0; kt < NT - 2; ++kt) {
        VM8; BAR;              // tile kt landed (block-wide after barrier)
        COMPUTE(c);
        BAR;                   // all waves done reading buffer c
        if (kt + 3 < NT) STAGE(c, kt + 3);
        c = (c == 2) ? 0 : c + 1;
    }
    VM4; BAR;                  // tile NT-2 landed
    COMPUTE(c);
    BAR;
    c = (c == 2) ? 0 : c + 1;
    VM0; BAR;                  // tile NT-1 landed
    COMPUTE(c);

    float e0 = 0.f, e1 = 0.f;
    if constexpr (EPI == 4) { e0 = scal2[0]; e1 = scal2[1]; }

#pragma unroll
    for (int i = 0; i < 4; ++i) {
        const long rb = m0 + wm * 64 + i * 16 + kg * 4;
#pragma unroll
        for (int j = 0; j < 4; ++j) {
            const long cc = n0 + wn * 64 + j * 16 + fr;
#pragma unroll
            for (int r = 0; r < 4; ++r) {
                const long rr = rb + r;
                const float v = acc[i][j][r];
                const long idx = z * sC + rr * ldc + cc;
                if constexpr (EPI == 0)      ((bf16*)Cout)[idx] = (bf16)(v + biasCol[cc]);
                else if constexpr (EPI == 1) ((bf16*)Cout)[idx] = (bf16)(v + biasRow[rr]);
                else if constexpr (EPI == 2) ((bf16*)Cout)[idx] = (bf16)(v * scale);
                else if constexpr (EPI == 3) ((bf16*)Cout)[idx] = (bf16)v;
                else if constexpr (EPI == 4) ((bf16*)Cout)[idx] = (bf16)(v * e0 + e1);
                else ((bf16*)Cout)[idx] = (bf16)(v + (float)((const bf16*)Res)[z * sRes + rr * ldc + cc] + biasCol[cc]);
            }
        }
    }
}

// ---------------------------------------------------------------------------
// Row softmax, bf16 in -> bf16 out, IN-PLACE (P aliases S). Scale pre-applied.
// ---------------------------------------------------------------------------
template<int W>
__global__ __launch_bounds__(256)
void softmax_rows(const bf16* __restrict__ S, bf16* __restrict__ P)
{
    constexpr int NV = W / 256;
    const long row = blockIdx.x;
    const int t = threadIdx.x;
    const bf16* src = S + row * (long)W + t * NV;
    bf16* dst = P + row * (long)W + t * NV;

    float v[NV];
    if constexpr (NV == 4) { bf16x4 x = *(const bf16x4*)src;
        v[0] = (float)x[0]; v[1] = (float)x[1]; v[2] = (float)x[2]; v[3] = (float)x[3]; }
    else { bf16x2 x = *(const bf16x2*)src; v[0] = (float)x[0]; v[1] = (float)x[1]; }

    float m = v[0];
#pragma unroll
    for (int i = 1; i < NV; ++i) m = fmaxf(m, v[i]);
#pragma unroll
    for (int o = 32; o > 0; o >>= 1) m = fmaxf(m, __shfl_xor(m, o));
    __shared__ float red[8];
    const int w = t >> 6, l = t & 63;
    if (l == 0) red[w] = m;
    __syncthreads();
    m = fmaxf(fmaxf(red[0], red[1]), fmaxf(red[2], red[3]));

    float s = 0.f;
#pragma unroll
    for (int i = 0; i < NV; ++i) { v[i] = __expf(v[i] - m); s += v[i]; }
#pragma unroll
    for (int o = 32; o > 0; o >>= 1) s += __shfl_xor(s, o);
    if (l == 0) red[4 + w] = s;
    __syncthreads();
    s = red[4] + red[5] + red[6] + red[7];
    const float inv = 1.f / s;

    if constexpr (NV == 4) {
        bf16x4 o4;
#pragma unroll
        for (int i = 0; i < 4; ++i) o4[i] = (bf16)(v[i] * inv);
        *(bf16x4*)dst = o4;
    } else {
        bf16x2 o2;
#pragma unroll
        for (int i = 0; i < 2; ++i) o2[i] = (bf16)(v[i] * inv);
        *(bf16x2*)dst = o2;
    }
}

// ---------------------------------------------------------------------------
// LayerNorm over rows of 512, bf16 in. OUTBF=1 -> bf16 out, else f32 out.
// ---------------------------------------------------------------------------
template<int OUTBF>
__global__ __launch_bounds__(128)
void ln_rows(const bf16* __restrict__ X, const float* __restrict__ g,
             const float* __restrict__ bta, void* __restrict__ out)
{
    const long row = blockIdx.x;
    const int t = threadIdx.x;
    bf16x4 b4 = *(const bf16x4*)(X + row * 512 + t * 4);
    float v[4] = { (float)b4[0], (float)b4[1], (float)b4[2], (float)b4[3] };
    float s1 = v[0] + v[1] + v[2] + v[3];
    float s2 = v[0]*v[0] + v[1]*v[1] + v[2]*v[2] + v[3]*v[3];
#pragma unroll
    for (int o = 32; o > 0; o >>= 1) { s1 += __shfl_xor(s1, o); s2 += __shfl_xor(s2, o); }
    __shared__ float r1[2], r2[2];
    const int w = t >> 6, l = t & 63;
    if (l == 0) { r1[w] = s1; r2[w] = s2; }
    __syncthreads();
    s1 = r1[0] + r1[1];
    s2 = r2[0] + r2[1];
    const float mean = s1 * (1.f / 512.f);
    const float var  = s2 * (1.f / 512.f) - mean * mean;
    const float rstd = rsqrtf(var + 1e-5f);
    const int c = t * 4;
    if constexpr (OUTBF) {
        bf16x4 o4;
#pragma unroll
        for (int k = 0; k < 4; ++k) o4[k] = (bf16)((v[k] - mean) * rstd * g[c + k] + bta[c + k]);
        *(bf16x4*)((bf16*)out + row * 512 + c) = o4;
    } else {
        f32x4 o4;
#pragma unroll
        for (int k = 0; k < 4; ++k) o4[k] = (v[k] - mean) * rstd * g[c + k] + bta[c + k];
        *(f32x4*)((float*)out + row * 512 + c) = o4;
    }
}

// ---------------------------------------------------------------------------
__global__ __launch_bounds__(256)
void transpose_cvt(const float* __restrict__ x, bf16* __restrict__ Xb, bf16* __restrict__ xt)
{
    __shared__ bf16 tile[32][33];
    const int b = blockIdx.z;
    const int n0 = blockIdx.x * 32, l0 = blockIdx.y * 32;
    const long base = (long)b * N_ID * L_IN;
    const int tx = threadIdx.x, ty = threadIdx.y;
#pragma unroll
    for (int i = ty; i < 32; i += 8) {
        const long idx = base + (long)(n0 + i) * L_IN + l0 + tx;
        const bf16 s = (bf16)x[idx];
        Xb[idx] = s;
        tile[i][tx] = s;
    }
    __syncthreads();
#pragma unroll
    for (int i = ty; i < 32; i += 8)
        xt[base + (long)(l0 + i) * N_ID + n0 + tx] = tile[tx][i];
}

struct Ptr6 { const float* s[6]; bf16* d[6]; };

__global__ void cvt_multi(Ptr6 p, int n)   // 4 elems/thread
{
    const int j = blockIdx.y;
    const int i = (blockIdx.x * 256 + threadIdx.x) * 4;
    if (i < n) {
        f32x4 v = *(const f32x4*)(p.s[j] + i);
        bf16x4 o; o[0] = (bf16)v[0]; o[1] = (bf16)v[1]; o[2] = (bf16)v[2]; o[3] = (bf16)v[3];
        *(bf16x4*)(p.d[j] + i) = o;
    }
}

__global__ void wo_sum2(const float* __restrict__ a, const float* __restrict__ b,
                        bf16* __restrict__ da, bf16* __restrict__ db)
{
    const int i = blockIdx.x * 256 + threadIdx.x; // < 262144
    const float* src = blockIdx.y ? b : a;
    bf16* dst = blockIdx.y ? db : da;
    const float* p = src + (long)i * 8;
    float s = 0.f;
#pragma unroll
    for (int h = 0; h < 8; ++h) s += p[h];
    dst[i] = (bf16)s;
}

__global__ void concat2(const float* __restrict__ a, const float* __restrict__ b,
                        float* __restrict__ out, int n)
{
    const int i = blockIdx.x * 256 + threadIdx.x;
    if (i < n) { out[i] = a[i]; out[n + i] = b[i]; }
}

__global__ void prep_scal(const float* __restrict__ W1, const float* __restrict__ b1, float* __restrict__ out)
{
    if (threadIdx.x == 0 && blockIdx.x == 0) {
        float s = 0.f;
        for (int h = 0; h < 8; ++h) s += W1[h];
        out[0] = s;
        out[1] = b1[0];
    }
}

// ---------------------------------------------------------------------------
static void launch_gemm(int epi, const bf16* A, const bf16* B, void* C,
                        const float* bc, const float* br, const void* res, const float* sc2,
                        float scale, int M, int N, int K,
                        long lda, long ldb, long ldc,
                        long sA, long sB, long sC, long sRes, int batches, hipStream_t st)
{
    const unsigned gx = M / 128, gy = N / 128;
    const unsigned gxy = gx * gy, nwg = gxy * (unsigned)batches;
    dim3 g(nwg), blk(256);
    switch (epi) {
    case 0: gemm3<0><<<g, blk, 0, st>>>(A, B, C, bc, br, res, sc2, scale, K, lda, ldb, ldc, sA, sB, sC, sRes, gy, gxy, nwg); break;
    case 1: gemm3<1><<<g, blk, 0, st>>>(A, B, C, bc, br, res, sc2, scale, K, lda, ldb, ldc, sA, sB, sC, sRes, gy, gxy, nwg); break;
    case 2: gemm3<2><<<g, blk, 0, st>>>(A, B, C, bc, br, res, sc2, scale, K, lda, ldb, ldc, sA, sB, sC, sRes, gy, gxy, nwg); break;
    case 3: gemm3<3><<<g, blk, 0, st>>>(A, B, C, bc, br, res, sc2, scale, K, lda, ldb, ldc, sA, sB, sC, sRes, gy, gxy, nwg); break;
    case 4: gemm3<4><<<g, blk, 0, st>>>(A, B, C, bc, br, res, sc2, scale, K, lda, ldb, ldc, sA, sB, sC, sRes, gy, gxy, nwg); break;
    default: gemm3<5><<<g, blk, 0, st>>>(A, B, C, bc, br, res, sc2, scale, K, lda, ldb, ldc, sA, sB, sC, sRes, gy, gxy, nwg); break;
    }
}

extern "C" void kernel_launch(void* const* d_in, const int* in_sizes, int n_in,
                              void* d_out, int out_size, void* d_ws, size_t ws_size,
                              hipStream_t stream)
{
    (void)in_sizes; (void)n_in; (void)out_size;

    const float* x   = (const float*)d_in[0];
    const float* tWq = (const float*)d_in[1];  const float* tbq = (const float*)d_in[2];
    const float* tWk = (const float*)d_in[3];  const float* tbk = (const float*)d_in[4];
    const float* tWv = (const float*)d_in[5];  const float* tbv = (const float*)d_in[6];
    const float* tWo = (const float*)d_in[7];  const float* tbo = (const float*)d_in[8];
    const float* tg  = (const float*)d_in[9];  const float* tb  = (const float*)d_in[10];
    const float* cWq = (const float*)d_in[11]; const float* cbq = (const float*)d_in[12];
    const float* cWk = (const float*)d_in[13]; const float* cbk = (const float*)d_in[14];
    const float* cWv = (const float*)d_in[15]; const float* cbv = (const float*)d_in[16];
    const float* cWo = (const float*)d_in[17]; const float* cbo = (const float*)d_in[18];
    const float* cg  = (const float*)d_in[19]; const float* cb  = (const float*)d_in[20];
    const float* sWq = (const float*)d_in[21]; const float* sbq = (const float*)d_in[22];
    const float* sWk = (const float*)d_in[23]; const float* sbk = (const float*)d_in[24];
    const float* sWv = (const float*)d_in[25]; const float* sbv = (const float*)d_in[26];
    const float* sW1 = (const float*)d_in[27]; const float* sb1 = (const float*)d_in[28];

    char* p = (char*)d_ws;
    auto alloc = [&](size_t bytes) -> char* {
        char* r = p; p += (bytes + 255) & ~(size_t)255; return r;
    };

    // merged [Wq|Wk] (row-concat) per stage; separate Wv
    bf16* WqkT = (bf16*)alloc(2 * 262144 * 2);
    bf16* WvT  = (bf16*)alloc(262144 * 2);
    bf16* WqC  = (bf16*)alloc(262144 * 2);  bf16* WkC = (bf16*)alloc(262144 * 2);  bf16* WvC = (bf16*)alloc(262144 * 2);
    bf16* WqkS = (bf16*)alloc(2 * 1048576 * 2);
    bf16* WvS  = (bf16*)alloc(1048576 * 2);
    bf16* WsT  = (bf16*)alloc(262144 * 2);  bf16* WsC = (bf16*)alloc(262144 * 2);
    float* scal = (float*)alloc(256);
    float* bqkT = (float*)alloc(1024 * 4);
    float* sbqk = (float*)alloc(2048 * 4);

    const size_t ACT_B = (size_t)ACT_E * 2;
    bf16* bufQK = (bf16*)alloc(2 * ACT_B);  // [32768,1024] or [16384,2048]; Lm -> Q half
    bf16* Xb    = (bf16*)alloc(ACT_B);      // reused as SO after stage T
    bf16* xt    = (bf16*)alloc(ACT_B);
    bf16* bufV  = (bf16*)alloc(ACT_B);
    bf16* TO    = (bf16*)alloc(ACT_B);
    bf16* PL    = (bf16*)alloc(ACT_B);      // preLN scratch

    size_t used = (size_t)(p - (char*)d_ws);
    int CB = 32;
    while (CB > 1 && used + (size_t)CB * 2097152ULL + 4096 > ws_size) CB >>= 1;
    bf16* Sbuf = (bf16*)alloc((size_t)CB * 2097152ULL);
    bf16* Pbuf = Sbuf;   // softmax in-place

    const float rsc_t = 0.08838834764831845f;  // 1/sqrt(1024/8)
    const float rsc_s = 0.125f;                // 1/sqrt(512/8)

    // ---- prep ----
    Ptr6 smallW;
    smallW.s[0] = tWq; smallW.s[1] = tWk; smallW.s[2] = tWv;
    smallW.s[3] = cWq; smallW.s[4] = cWk; smallW.s[5] = cWv;
    smallW.d[0] = WqkT; smallW.d[1] = WqkT + 262144; smallW.d[2] = WvT;
    smallW.d[3] = WqC;  smallW.d[4] = WkC;           smallW.d[5] = WvC;
    cvt_multi<<<dim3(256, 6), dim3(256), 0, stream>>>(smallW, 262144);
    Ptr6 bigW = {};
    bigW.s[0] = sWq;  bigW.s[1] = sWk;            bigW.s[2] = sWv;
    bigW.d[0] = WqkS; bigW.d[1] = WqkS + 1048576; bigW.d[2] = WvS;
    cvt_multi<<<dim3(1024, 3), dim3(256), 0, stream>>>(bigW, 1048576);
    wo_sum2<<<dim3(1024, 2), dim3(256), 0, stream>>>(tWo, cWo, WsT, WsC);
    concat2<<<dim3(2), dim3(256), 0, stream>>>(tbq, tbk, bqkT, 512);
    concat2<<<dim3(4), dim3(256), 0, stream>>>(sbq, sbk, sbqk, 1024);
    prep_scal<<<dim3(1), dim3(64), 0, stream>>>(sW1, sb1, scal);
    transpose_cvt<<<dim3(32, 16, BATCH), dim3(32, 8), 0, stream>>>(x, Xb, xt);

    // time/cross attention: QK^T*rsc -> softmax -> Lm = P@Vt^T (Lm -> Q half of bufQK)
    auto attn_tc = [&](float rsc) {
        for (int c0 = 0; c0 < BATCH; c0 += CB) {
            const long offQ = (long)c0 * S_TT;
            const long offV = (long)c0 * S_NL;
            launch_gemm(2, bufQK + offQ, bufQK + 512 + offQ, Sbuf, nullptr, nullptr, nullptr, nullptr, rsc,
                        1024, 1024, 512, 1024, 1024, 1024, S_TT, S_TT, S_TT, 0, CB, stream);
            softmax_rows<1024><<<dim3(CB * 1024), dim3(256), 0, stream>>>(Sbuf, Pbuf);
            // Lm[n,l] = sum_j P[n,j] * Vt[l,j]; Vt stored [512,1024] -> ldb = 1024
            launch_gemm(3, Pbuf, bufV + offV, bufQK + offQ, nullptr, nullptr, nullptr, nullptr, 0.f,
                        1024, 512, 1024, 1024, 1024, 1024, S_TT, S_NL, S_TT, 0, CB, stream);
        }
    };

    // ==== Stage T (time de_att) ====
    launch_gemm(0, Xb, WqkT, bufQK, bqkT, nullptr, nullptr, nullptr, 0.f,
                32768, 1024, 512, 512, 512, 1024, 0, 0, 0, 0, 1, stream);
    launch_gemm(1, WvT, Xb, bufV, nullptr, tbv, nullptr, nullptr, 0.f,
                512, 1024, 512, 512, 512, 1024, 0, S_NL, S_NL, 0, BATCH, stream);
    attn_tc(rsc_t);
    launch_gemm(5, bufQK, WsT, PL, tbo, nullptr, Xb, nullptr, 0.f,
                32768, 512, 512, 1024, 512, 512, 0, 0, 0, 0, 1, stream);
    ln_rows<1><<<dim3(32768), dim3(128), 0, stream>>>(PL, tg, tb, TO);

    // ==== Stage S (space attention) ====
    bf16* SOp = Xb;   // Xb dead after stage T -> space_out
    launch_gemm(0, xt, WqkS, bufQK, sbqk, nullptr, nullptr, nullptr, 0.f,
                16384, 2048, 1024, 1024, 1024, 2048, 0, 0, 0, 0, 1, stream);
    launch_gemm(1, WvS, xt, bufV, nullptr, sbv, nullptr, nullptr, 0.f,
                1024, 512, 1024, 1024, 1024, 512, 0, S_NL, S_NL, 0, BATCH, stream);
    for (int c0 = 0; c0 < BATCH; c0 += CB) {
        const long offQ = (long)c0 * S_TT;       // 512*2048 = S_TT per batch
        const long offV = (long)c0 * S_NL;
        launch_gemm(2, bufQK + offQ, bufQK + 1024 + offQ, Sbuf, nullptr, nullptr, nullptr, nullptr, rsc_s,
                    512, 512, 1024, 2048, 2048, 512, S_TT, S_TT, (long)L_IN * L_IN, 0, CB, stream);
        softmax_rows<512><<<dim3(CB * 512), dim3(256), 0, stream>>>(Sbuf, Pbuf);
        launch_gemm(4, bufV + offV, Pbuf, SOp + offV, nullptr, nullptr, nullptr, scal, 0.f,
                    1024, 512, 512, 512, 512, 512, S_NL, (long)L_IN * L_IN, S_NL, 0, CB, stream);
    }

    // ==== Stage C (cross de_att) ====
    launch_gemm(0, SOp, WqC, bufQK, cbq, nullptr, nullptr, nullptr, 0.f,
                32768, 512, 512, 512, 512, 1024, 0, 0, 0, 0, 1, stream);
    launch_gemm(0, TO, WkC, bufQK + 512, cbk, nullptr, nullptr, nullptr, 0.f,
                32768, 512, 512, 512, 512, 1024, 0, 0, 0, 0, 1, stream);
    launch_gemm(1, WvC, TO, bufV, nullptr, cbv, nullptr, nullptr, 0.f,
                512, 1024, 512, 512, 512, 1024, 0, S_NL, S_NL, 0, BATCH, stream);
    attn_tc(rsc_t);
    launch_gemm(5, bufQK, WsC, PL, cbo, nullptr, TO, nullptr, 0.f,
                32768, 512, 512, 1024, 512, 512, 0, 0, 0, 0, 1, stream);
    ln_rows<0><<<dim3(32768), dim3(128), 0, stream>>>(PL, cg, cb, d_out);
}

// Round 9
// 830.121 us; speedup vs baseline: 1.1353x; 1.0554x over previous
//
#include <hip/hip_runtime.h>
#include <hip/hip_bf16.h>

typedef __bf16 bf16;
typedef __bf16 bf16x8 __attribute__((ext_vector_type(8)));
typedef __bf16 bf16x4 __attribute__((ext_vector_type(4)));
typedef __bf16 bf16x2 __attribute__((ext_vector_type(2)));
typedef float f32x4 __attribute__((ext_vector_type(4)));
typedef float f32x2 __attribute__((ext_vector_type(2)));

#define BATCH 32
#define N_ID 1024
#define L_IN 512

static const long ACT_E = (long)BATCH * N_ID * L_IN;   // 16,777,216
static const long S_NL  = (long)N_ID * L_IN;           // 524288
static const long S_TT  = (long)N_ID * N_ID;           // 1048576

__device__ __forceinline__ void gload16(const bf16* g, bf16* l)
{
    __builtin_amdgcn_global_load_lds((__attribute__((address_space(1))) void*)g,
                                     (__attribute__((address_space(3))) void*)l, 16, 0, 0);
}

// ---------------------------------------------------------------------------
// 128x128 BK=32 triple-buffered counted-vmcnt NT GEMM (3 blocks/CU).
// C[m,n] = sum_k A[m,k]*B[n,k]; strides lda/ldb/ldc decoupled.
// EPI: 0 bf16=acc+biasCol[n]; 1 bf16=acc+biasRow[m]; 2 bf16=acc*scale;
//      3 bf16=acc; 4 bf16=acc*scal2[0]+scal2[1]; 5 bf16=acc+ResBF16+biasCol[n]
// ---------------------------------------------------------------------------
#define VM8 asm volatile("s_waitcnt vmcnt(8)" ::: "memory")
#define VM4 asm volatile("s_waitcnt vmcnt(4)" ::: "memory")
#define VM0 asm volatile("s_waitcnt vmcnt(0)" ::: "memory")
#define BAR __builtin_amdgcn_s_barrier()

#define COMPUTE(CIDX) \
    { \
      const bf16* pa = ldsb + (CIDX) * 8192; \
      const bf16* pb = pa + 4096; \
      bf16x8 af[4], bfv[4]; \
_Pragma("unroll") \
      for (int i = 0; i < 4; ++i) \
        af[i] = *(const bf16x8*)(pa + (wm * 64 + i * 16 + fr) * 32 + slotk); \
_Pragma("unroll") \
      for (int j = 0; j < 4; ++j) \
        bfv[j] = *(const bf16x8*)(pb + (wn * 64 + j * 16 + fr) * 32 + slotk); \
      __builtin_amdgcn_s_setprio(1); \
_Pragma("unroll") \
      for (int i = 0; i < 4; ++i) \
_Pragma("unroll") \
        for (int j = 0; j < 4; ++j) \
          acc[i][j] = __builtin_amdgcn_mfma_f32_16x16x32_bf16(af[i], bfv[j], acc[i][j], 0, 0, 0); \
      __builtin_amdgcn_s_setprio(0); \
    }

#define STAGE(CIDX, KT) { stg(ldsb + (CIDX) * 8192, Ab, lda, m0, KT); \
                          stg(ldsb + (CIDX) * 8192 + 4096, Bb, ldb, n0, KT); }

template<int EPI>
__global__ __launch_bounds__(256, 3)
void gemm3(const bf16* __restrict__ A, const bf16* __restrict__ Bm, void* __restrict__ Cout,
           const float* __restrict__ biasCol, const float* __restrict__ biasRow,
           const void* __restrict__ Res, const float* __restrict__ scal2,
           float scale, int K,
           long lda, long ldb, long ldc,
           long sA, long sB, long sC, long sRes,
           unsigned gy, unsigned gxy, unsigned nwg)
{
    __shared__ __align__(16) bf16 ldsbuf[3 * 2 * 4096];   // 48 KB
    bf16* ldsb = ldsbuf;

    unsigned id = blockIdx.x;
    {
        const unsigned q = nwg >> 3, r = nwg & 7;
        const unsigned xcd = id & 7, off = id >> 3;
        id = (xcd < r ? xcd * (q + 1) : r * (q + 1) + (xcd - r) * q) + off;
    }
    const unsigned bz = id / gxy;
    const unsigned rem = id - bz * gxy;
    const unsigned bx = rem / gy;        // M-tile: slow (A-panel reuse)
    const unsigned by = rem - bx * gy;   // N-tile: fastest

    const int t = threadIdx.x;
    const int w = t >> 6;
    const int lane = t & 63;
    const int fr = lane & 15;
    const int kg = lane >> 4;
    const int wm = w >> 1, wn = w & 1;
    const long z = bz;
    const long m0 = (long)bx * 128;
    const long n0 = (long)by * 128;
    const bf16* Ab = A + z * sA;
    const bf16* Bb = Bm + z * sB;

    const int srow = w * 16 + (lane >> 2);
    const int gc = (lane & 3) ^ ((lane >> 3) & 3);
    const int slotk = (kg ^ ((fr >> 1) & 3)) * 8;

    auto stg = [&](bf16* dst, const bf16* base, long ld, long rc0, int kt) {
#pragma unroll
        for (int r = 0; r < 2; ++r) {
            const int row = r * 64 + srow;
            const bf16* src = base + (rc0 + row) * ld + kt * 32 + gc * 8;
            gload16(src, dst + row * 32 + (lane & 3) * 8);
        }
    };

    f32x4 acc[4][4] = {};

    const int NT = K >> 5;
    STAGE(0, 0); STAGE(1, 1); STAGE(2, 2);

    int c = 0;
    for (int kt = 0; kt < NT - 2; ++kt) {
        VM8; BAR;
        COMPUTE(c);
        BAR;
        if (kt + 3 < NT) STAGE(c, kt + 3);
        c = (c == 2) ? 0 : c + 1;
    }
    VM4; BAR;
    COMPUTE(c);
    BAR;
    c = (c == 2) ? 0 : c + 1;
    VM0; BAR;
    COMPUTE(c);

    float e0 = 0.f, e1 = 0.f;
    if constexpr (EPI == 4) { e0 = scal2[0]; e1 = scal2[1]; }

#pragma unroll
    for (int i = 0; i < 4; ++i) {
        const long rb = m0 + wm * 64 + i * 16 + kg * 4;
#pragma unroll
        for (int j = 0; j < 4; ++j) {
            const long cc = n0 + wn * 64 + j * 16 + fr;
#pragma unroll
            for (int r = 0; r < 4; ++r) {
                const long rr = rb + r;
                const float v = acc[i][j][r];
                const long idx = z * sC + rr * ldc + cc;
                if constexpr (EPI == 0)      ((bf16*)Cout)[idx] = (bf16)(v + biasCol[cc]);
                else if constexpr (EPI == 1) ((bf16*)Cout)[idx] = (bf16)(v + biasRow[rr]);
                else if constexpr (EPI == 2) ((bf16*)Cout)[idx] = (bf16)(v * scale);
                else if constexpr (EPI == 3) ((bf16*)Cout)[idx] = (bf16)v;
                else if constexpr (EPI == 4) ((bf16*)Cout)[idx] = (bf16)(v * e0 + e1);
                else ((bf16*)Cout)[idx] = (bf16)(v + (float)((const bf16*)Res)[z * sRes + rr * ldc + cc] + biasCol[cc]);
            }
        }
    }
}

// ---------------------------------------------------------------------------
template<int W>
__global__ __launch_bounds__(256)
void softmax_rows(const bf16* __restrict__ S, bf16* __restrict__ P)
{
    constexpr int NV = W / 256;
    const long row = blockIdx.x;
    const int t = threadIdx.x;
    const bf16* src = S + row * (long)W + t * NV;
    bf16* dst = P + row * (long)W + t * NV;

    float v[NV];
    if constexpr (NV == 4) { bf16x4 x = *(const bf16x4*)src;
        v[0] = (float)x[0]; v[1] = (float)x[1]; v[2] = (float)x[2]; v[3] = (float)x[3]; }
    else { bf16x2 x = *(const bf16x2*)src; v[0] = (float)x[0]; v[1] = (float)x[1]; }

    float m = v[0];
#pragma unroll
    for (int i = 1; i < NV; ++i) m = fmaxf(m, v[i]);
#pragma unroll
    for (int o = 32; o > 0; o >>= 1) m = fmaxf(m, __shfl_xor(m, o));
    __shared__ float red[8];
    const int w = t >> 6, l = t & 63;
    if (l == 0) red[w] = m;
    __syncthreads();
    m = fmaxf(fmaxf(red[0], red[1]), fmaxf(red[2], red[3]));

    float s = 0.f;
#pragma unroll
    for (int i = 0; i < NV; ++i) { v[i] = __expf(v[i] - m); s += v[i]; }
#pragma unroll
    for (int o = 32; o > 0; o >>= 1) s += __shfl_xor(s, o);
    if (l == 0) red[4 + w] = s;
    __syncthreads();
    s = red[4] + red[5] + red[6] + red[7];
    const float inv = 1.f / s;

    if constexpr (NV == 4) {
        bf16x4 o4;
#pragma unroll
        for (int i = 0; i < 4; ++i) o4[i] = (bf16)(v[i] * inv);
        *(bf16x4*)dst = o4;
    } else {
        bf16x2 o2;
#pragma unroll
        for (int i = 0; i < 2; ++i) o2[i] = (bf16)(v[i] * inv);
        *(bf16x2*)dst = o2;
    }
}

// ---------------------------------------------------------------------------
template<int OUTBF>
__global__ __launch_bounds__(128)
void ln_rows(const bf16* __restrict__ X, const float* __restrict__ g,
             const float* __restrict__ bta, void* __restrict__ out)
{
    const long row = blockIdx.x;
    const int t = threadIdx.x;
    bf16x4 b4 = *(const bf16x4*)(X + row * 512 + t * 4);
    float v[4] = { (float)b4[0], (float)b4[1], (float)b4[2], (float)b4[3] };
    float s1 = v[0] + v[1] + v[2] + v[3];
    float s2 = v[0]*v[0] + v[1]*v[1] + v[2]*v[2] + v[3]*v[3];
#pragma unroll
    for (int o = 32; o > 0; o >>= 1) { s1 += __shfl_xor(s1, o); s2 += __shfl_xor(s2, o); }
    __shared__ float r1[2], r2[2];
    const int w = t >> 6, l = t & 63;
    if (l == 0) { r1[w] = s1; r2[w] = s2; }
    __syncthreads();
    s1 = r1[0] + r1[1];
    s2 = r2[0] + r2[1];
    const float mean = s1 * (1.f / 512.f);
    const float var  = s2 * (1.f / 512.f) - mean * mean;
    const float rstd = rsqrtf(var + 1e-5f);
    const int c = t * 4;
    if constexpr (OUTBF) {
        bf16x4 o4;
#pragma unroll
        for (int k = 0; k < 4; ++k) o4[k] = (bf16)((v[k] - mean) * rstd * g[c + k] + bta[c + k]);
        *(bf16x4*)((bf16*)out + row * 512 + c) = o4;
    } else {
        f32x4 o4;
#pragma unroll
        for (int k = 0; k < 4; ++k) o4[k] = (v[k] - mean) * rstd * g[c + k] + bta[c + k];
        *(f32x4*)((float*)out + row * 512 + c) = o4;
    }
}

// ---------------------------------------------------------------------------
__global__ __launch_bounds__(256)
void transpose_cvt(const float* __restrict__ x, bf16* __restrict__ Xb, bf16* __restrict__ xt)
{
    __shared__ bf16 tile[32][33];
    const int b = blockIdx.z;
    const int n0 = blockIdx.x * 32, l0 = blockIdx.y * 32;
    const long base = (long)b * N_ID * L_IN;
    const int tx = threadIdx.x, ty = threadIdx.y;
#pragma unroll
    for (int i = ty; i < 32; i += 8) {
        const long idx = base + (long)(n0 + i) * L_IN + l0 + tx;
        const bf16 s = (bf16)x[idx];
        Xb[idx] = s;
        tile[i][tx] = s;
    }
    __syncthreads();
#pragma unroll
    for (int i = ty; i < 32; i += 8)
        xt[base + (long)(l0 + i) * N_ID + n0 + tx] = tile[tx][i];
}

// 512x512 f32 -> transposed bf16 (two jobs via z)
__global__ __launch_bounds__(256)
void transpose512_cvt(const float* __restrict__ a, const float* __restrict__ b,
                      bf16* __restrict__ da, bf16* __restrict__ db)
{
    __shared__ bf16 tile[32][33];
    const float* src = blockIdx.z ? b : a;
    bf16* dst = blockIdx.z ? db : da;
    const int c0 = blockIdx.x * 32, r0 = blockIdx.y * 32;
    const int tx = threadIdx.x, ty = threadIdx.y;
#pragma unroll
    for (int i = ty; i < 32; i += 8)
        tile[i][tx] = (bf16)src[(long)(r0 + i) * 512 + c0 + tx];
    __syncthreads();
#pragma unroll
    for (int i = ty; i < 32; i += 8)
        dst[(long)(c0 + i) * 512 + r0 + tx] = tile[tx][i];
}

struct Ptr6 { const float* s[6]; bf16* d[6]; };

__global__ void cvt_multi(Ptr6 p, int n)
{
    const int j = blockIdx.y;
    const int i = (blockIdx.x * 256 + threadIdx.x) * 4;
    if (i < n) {
        f32x4 v = *(const f32x4*)(p.s[j] + i);
        bf16x4 o; o[0] = (bf16)v[0]; o[1] = (bf16)v[1]; o[2] = (bf16)v[2]; o[3] = (bf16)v[3];
        *(bf16x4*)(p.d[j] + i) = o;
    }
}

__global__ void wo_sum2(const float* __restrict__ a, const float* __restrict__ b,
                        bf16* __restrict__ da, bf16* __restrict__ db)
{
    const int i = blockIdx.x * 256 + threadIdx.x;
    const float* src = blockIdx.y ? b : a;
    bf16* dst = blockIdx.y ? db : da;
    const float* p = src + (long)i * 8;
    float s = 0.f;
#pragma unroll
    for (int h = 0; h < 8; ++h) s += p[h];
    dst[i] = (bf16)s;
}

// bias'[o] = bo[o] + sum_l Ws[o,l]*bv[l]   (one block of 64 per o)
__global__ __launch_bounds__(64)
void biasfold(const bf16* __restrict__ Ws, const float* __restrict__ bv,
              const float* __restrict__ bo, float* __restrict__ out)
{
    const int o = blockIdx.x;
    float s = 0.f;
    for (int l = threadIdx.x; l < 512; l += 64)
        s += (float)Ws[(long)o * 512 + l] * bv[l];
#pragma unroll
    for (int off = 32; off > 0; off >>= 1) s += __shfl_xor(s, off);
    if (threadIdx.x == 0) out[o] = bo[o] + s;
}

__global__ void concat2(const float* __restrict__ a, const float* __restrict__ b,
                        float* __restrict__ out, int n)
{
    const int i = blockIdx.x * 256 + threadIdx.x;
    if (i < n) { out[i] = a[i]; out[n + i] = b[i]; }
}

__global__ void prep_scal(const float* __restrict__ W1, const float* __restrict__ b1, float* __restrict__ out)
{
    if (threadIdx.x == 0 && blockIdx.x == 0) {
        float s = 0.f;
        for (int h = 0; h < 8; ++h) s += W1[h];
        out[0] = s;
        out[1] = b1[0];
    }
}

// ---------------------------------------------------------------------------
static void launch_gemm(int epi, const bf16* A, const bf16* B, void* C,
                        const float* bc, const float* br, const void* res, const float* sc2,
                        float scale, int M, int N, int K,
                        long lda, long ldb, long ldc,
                        long sA, long sB, long sC, long sRes, int batches, hipStream_t st)
{
    const unsigned gx = M / 128, gy = N / 128;
    const unsigned gxy = gx * gy, nwg = gxy * (unsigned)batches;
    dim3 g(nwg), blk(256);
    switch (epi) {
    case 0: gemm3<0><<<g, blk, 0, st>>>(A, B, C, bc, br, res, sc2, scale, K, lda, ldb, ldc, sA, sB, sC, sRes, gy, gxy, nwg); break;
    case 1: gemm3<1><<<g, blk, 0, st>>>(A, B, C, bc, br, res, sc2, scale, K, lda, ldb, ldc, sA, sB, sC, sRes, gy, gxy, nwg); break;
    case 2: gemm3<2><<<g, blk, 0, st>>>(A, B, C, bc, br, res, sc2, scale, K, lda, ldb, ldc, sA, sB, sC, sRes, gy, gxy, nwg); break;
    case 3: gemm3<3><<<g, blk, 0, st>>>(A, B, C, bc, br, res, sc2, scale, K, lda, ldb, ldc, sA, sB, sC, sRes, gy, gxy, nwg); break;
    case 4: gemm3<4><<<g, blk, 0, st>>>(A, B, C, bc, br, res, sc2, scale, K, lda, ldb, ldc, sA, sB, sC, sRes, gy, gxy, nwg); break;
    default: gemm3<5><<<g, blk, 0, st>>>(A, B, C, bc, br, res, sc2, scale, K, lda, ldb, ldc, sA, sB, sC, sRes, gy, gxy, nwg); break;
    }
}

extern "C" void kernel_launch(void* const* d_in, const int* in_sizes, int n_in,
                              void* d_out, int out_size, void* d_ws, size_t ws_size,
                              hipStream_t stream)
{
    (void)in_sizes; (void)n_in; (void)out_size;

    const float* x   = (const float*)d_in[0];
    const float* tWq = (const float*)d_in[1];  const float* tbq = (const float*)d_in[2];
    const float* tWk = (const float*)d_in[3];  const float* tbk = (const float*)d_in[4];
    const float* tWv = (const float*)d_in[5];  const float* tbv = (const float*)d_in[6];
    const float* tWo = (const float*)d_in[7];  const float* tbo = (const float*)d_in[8];
    const float* tg  = (const float*)d_in[9];  const float* tb  = (const float*)d_in[10];
    const float* cWq = (const float*)d_in[11]; const float* cbq = (const float*)d_in[12];
    const float* cWk = (const float*)d_in[13]; const float* cbk = (const float*)d_in[14];
    const float* cWv = (const float*)d_in[15]; const float* cbv = (const float*)d_in[16];
    const float* cWo = (const float*)d_in[17]; const float* cbo = (const float*)d_in[18];
    const float* cg  = (const float*)d_in[19]; const float* cb  = (const float*)d_in[20];
    const float* sWq = (const float*)d_in[21]; const float* sbq = (const float*)d_in[22];
    const float* sWk = (const float*)d_in[23]; const float* sbk = (const float*)d_in[24];
    const float* sWv = (const float*)d_in[25]; const float* sbv = (const float*)d_in[26];
    const float* sW1 = (const float*)d_in[27]; const float* sb1 = (const float*)d_in[28];

    char* p = (char*)d_ws;
    auto alloc = [&](size_t bytes) -> char* {
        char* r = p; p += (bytes + 255) & ~(size_t)255; return r;
    };

    bf16* WqkT = (bf16*)alloc(2 * 262144 * 2);   // [Wq|Wk] time
    bf16* WqC  = (bf16*)alloc(262144 * 2);  bf16* WkC = (bf16*)alloc(262144 * 2);
    bf16* WqkS = (bf16*)alloc(2 * 1048576 * 2);
    bf16* WvS  = (bf16*)alloc(1048576 * 2);
    bf16* WsT  = (bf16*)alloc(262144 * 2);  bf16* WsC = (bf16*)alloc(262144 * 2);
    bf16* WvTrT = (bf16*)alloc(262144 * 2); bf16* WvTrC = (bf16*)alloc(262144 * 2); // Wv^T
    bf16* WvWT = (bf16*)alloc(262144 * 2);  bf16* WvWC = (bf16*)alloc(262144 * 2);  // Wsum*Wv
    float* scal = (float*)alloc(256);
    float* bqkT = (float*)alloc(1024 * 4);
    float* sbqk = (float*)alloc(2048 * 4);
    float* biasT = (float*)alloc(512 * 4);
    float* biasC = (float*)alloc(512 * 4);

    const size_t ACT_B = (size_t)ACT_E * 2;
    bf16* bufQK = (bf16*)alloc(2 * ACT_B);  // [32768,1024] or [16384,2048]
    bf16* Xb    = (bf16*)alloc(ACT_B);      // reused as SO after stage T
    bf16* xt    = (bf16*)alloc(ACT_B);
    bf16* bufV  = (bf16*)alloc(ACT_B);      // VW^T (time/cross) or Vs^T (space)
    bf16* TO    = (bf16*)alloc(ACT_B);
    bf16* PL    = (bf16*)alloc(ACT_B);      // preLN scratch

    size_t used = (size_t)(p - (char*)d_ws);
    int CB = 32;
    while (CB > 1 && used + (size_t)CB * 2097152ULL + 4096 > ws_size) CB >>= 1;
    bf16* Sbuf = (bf16*)alloc((size_t)CB * 2097152ULL);
    bf16* Pbuf = Sbuf;   // softmax in-place

    const float rsc_t = 0.08838834764831845f;  // 1/sqrt(1024/8)
    const float rsc_s = 0.125f;                // 1/sqrt(512/8)

    // ---- prep ----
    Ptr6 smallW = {};
    smallW.s[0] = tWq; smallW.s[1] = tWk; smallW.s[2] = cWq; smallW.s[3] = cWk;
    smallW.d[0] = WqkT; smallW.d[1] = WqkT + 262144; smallW.d[2] = WqC; smallW.d[3] = WkC;
    cvt_multi<<<dim3(256, 4), dim3(256), 0, stream>>>(smallW, 262144);
    Ptr6 bigW = {};
    bigW.s[0] = sWq;  bigW.s[1] = sWk;            bigW.s[2] = sWv;
    bigW.d[0] = WqkS; bigW.d[1] = WqkS + 1048576; bigW.d[2] = WvS;
    cvt_multi<<<dim3(1024, 3), dim3(256), 0, stream>>>(bigW, 1048576);
    wo_sum2<<<dim3(1024, 2), dim3(256), 0, stream>>>(tWo, cWo, WsT, WsC);
    transpose512_cvt<<<dim3(16, 16, 2), dim3(32, 8), 0, stream>>>(tWv, cWv, WvTrT, WvTrC);
    biasfold<<<dim3(512), dim3(64), 0, stream>>>(WsT, tbv, tbo, biasT);
    biasfold<<<dim3(512), dim3(64), 0, stream>>>(WsC, cbv, cbo, biasC);
    // WvW = Wsum @ Wv : C[o,c] = sum_l WsT[o,l] * WvTr[c,l]
    launch_gemm(3, WsT, WvTrT, WvWT, nullptr, nullptr, nullptr, nullptr, 0.f,
                512, 512, 512, 512, 512, 512, 0, 0, 0, 0, 1, stream);
    launch_gemm(3, WsC, WvTrC, WvWC, nullptr, nullptr, nullptr, nullptr, 0.f,
                512, 512, 512, 512, 512, 512, 0, 0, 0, 0, 1, stream);
    concat2<<<dim3(2), dim3(256), 0, stream>>>(tbq, tbk, bqkT, 512);
    concat2<<<dim3(4), dim3(256), 0, stream>>>(sbq, sbk, sbqk, 1024);
    prep_scal<<<dim3(1), dim3(64), 0, stream>>>(sW1, sb1, scal);
    transpose_cvt<<<dim3(32, 16, BATCH), dim3(32, 8), 0, stream>>>(x, Xb, xt);

    // time/cross attention with fused output projection:
    // QK^T*rsc -> softmax -> preLN = P @ VW^T + Res + bias'  (direct to PL)
    auto attn_tc = [&](float rsc, const bf16* ResP, const float* biasP) {
        for (int c0 = 0; c0 < BATCH; c0 += CB) {
            const long offQ = (long)c0 * S_TT;
            const long offV = (long)c0 * S_NL;
            launch_gemm(2, bufQK + offQ, bufQK + 512 + offQ, Sbuf, nullptr, nullptr, nullptr, nullptr, rsc,
                        1024, 1024, 512, 1024, 1024, 1024, S_TT, S_TT, S_TT, 0, CB, stream);
            softmax_rows<1024><<<dim3(CB * 1024), dim3(256), 0, stream>>>(Sbuf, Pbuf);
            launch_gemm(5, Pbuf, bufV + offV, PL + offV, biasP, nullptr, ResP + offV, nullptr, 0.f,
                        1024, 512, 1024, 1024, 1024, 512, S_TT, S_NL, S_NL, S_NL, CB, stream);
        }
    };

    // ==== Stage T (time de_att) ====
    launch_gemm(0, Xb, WqkT, bufQK, bqkT, nullptr, nullptr, nullptr, 0.f,
                32768, 1024, 512, 512, 512, 1024, 0, 0, 0, 0, 1, stream);
    // VW^T[o,j] = sum_c WvW[o,c] * Xb[j,c]  (no bias; folded into biasT)
    launch_gemm(3, WvWT, Xb, bufV, nullptr, nullptr, nullptr, nullptr, 0.f,
                512, 1024, 512, 512, 512, 1024, 0, S_NL, S_NL, 0, BATCH, stream);
    attn_tc(rsc_t, Xb, biasT);
    ln_rows<1><<<dim3(32768), dim3(128), 0, stream>>>(PL, tg, tb, TO);

    // ==== Stage S (space attention) ====
    bf16* SOp = Xb;   // Xb dead after stage T -> space_out
    launch_gemm(0, xt, WqkS, bufQK, sbqk, nullptr, nullptr, nullptr, 0.f,
                16384, 2048, 1024, 1024, 1024, 2048, 0, 0, 0, 0, 1, stream);
    launch_gemm(1, WvS, xt, bufV, nullptr, sbv, nullptr, nullptr, 0.f,
                1024, 512, 1024, 1024, 1024, 512, 0, S_NL, S_NL, 0, BATCH, stream);
    for (int c0 = 0; c0 < BATCH; c0 += CB) {
        const long offQ = (long)c0 * S_TT;
        const long offV = (long)c0 * S_NL;
        launch_gemm(2, bufQK + offQ, bufQK + 1024 + offQ, Sbuf, nullptr, nullptr, nullptr, nullptr, rsc_s,
                    512, 512, 1024, 2048, 2048, 512, S_TT, S_TT, (long)L_IN * L_IN, 0, CB, stream);
        softmax_rows<512><<<dim3(CB * 512), dim3(256), 0, stream>>>(Sbuf, Pbuf);
        launch_gemm(4, bufV + offV, Pbuf, SOp + offV, nullptr, nullptr, nullptr, scal, 0.f,
                    1024, 512, 512, 512, 512, 512, S_NL, (long)L_IN * L_IN, S_NL, 0, CB, stream);
    }

    // ==== Stage C (cross de_att) ====
    launch_gemm(0, SOp, WqC, bufQK, cbq, nullptr, nullptr, nullptr, 0.f,
                32768, 512, 512, 512, 512, 1024, 0, 0, 0, 0, 1, stream);
    launch_gemm(0, TO, WkC, bufQK + 512, cbk, nullptr, nullptr, nullptr, 0.f,
                32768, 512, 512, 512, 512, 1024, 0, 0, 0, 0, 1, stream);
    launch_gemm(3, WvWC, TO, bufV, nullptr, nullptr, nullptr, nullptr, 0.f,
                512, 1024, 512, 512, 512, 1024, 0, S_NL, S_NL, 0, BATCH, stream);
    attn_tc(rsc_t, TO, biasC);
    ln_rows<0><<<dim3(32768), dim3(128), 0, stream>>>(PL, cg, cb, d_out);
}

// Round 10
// 794.811 us; speedup vs baseline: 1.1857x; 1.0444x over previous
//
#include <hip/hip_runtime.h>
#include <hip/hip_bf16.h>

typedef __bf16 bf16;
typedef __bf16 bf16x8 __attribute__((ext_vector_type(8)));
typedef __bf16 bf16x4 __attribute__((ext_vector_type(4)));
typedef __bf16 bf16x2 __attribute__((ext_vector_type(2)));
typedef float f32x4 __attribute__((ext_vector_type(4)));

#define BATCH 32
#define N_ID 1024
#define L_IN 512

static const long ACT_E = (long)BATCH * N_ID * L_IN;   // 16,777,216
static const long S_NL  = (long)N_ID * L_IN;           // 524288
static const long S_TT  = (long)N_ID * N_ID;           // 1048576

__device__ __forceinline__ void gload16(const bf16* g, bf16* l)
{
    __builtin_amdgcn_global_load_lds((__attribute__((address_space(1))) void*)g,
                                     (__attribute__((address_space(3))) void*)l, 16, 0, 0);
}

// ---------------------------------------------------------------------------
// 128x128 BK=32 triple-buffered counted-vmcnt NT GEMM (3 blocks/CU).
// C[m,n] = sum_k A[m,k]*B[n,k]; strides lda/ldb/ldc decoupled.
// EPI: 0 bf16=acc+biasCol[z*sBR+cc]; 1 bf16=acc+biasRow[m]; 3 bf16=acc;
//      6 bf16=exp(acc*scale)                      (QK^T, no-max softmax)
//      7 bf16=acc*rowInv[z*sBR+rr]+ResBF16+biasCol[cc]   (time/cross PV)
//      8 bf16=acc*colInv[z*sBR+cc]*scal2[0]+scal2[1]     (space PV)
// ---------------------------------------------------------------------------
#define VM8 asm volatile("s_waitcnt vmcnt(8)" ::: "memory")
#define VM4 asm volatile("s_waitcnt vmcnt(4)" ::: "memory")
#define VM0 asm volatile("s_waitcnt vmcnt(0)" ::: "memory")
#define BAR __builtin_amdgcn_s_barrier()

#define COMPUTE(CIDX) \
    { \
      const bf16* pa = ldsb + (CIDX) * 8192; \
      const bf16* pb = pa + 4096; \
      bf16x8 af[4], bfv[4]; \
_Pragma("unroll") \
      for (int i = 0; i < 4; ++i) \
        af[i] = *(const bf16x8*)(pa + (wm * 64 + i * 16 + fr) * 32 + slotk); \
_Pragma("unroll") \
      for (int j = 0; j < 4; ++j) \
        bfv[j] = *(const bf16x8*)(pb + (wn * 64 + j * 16 + fr) * 32 + slotk); \
      __builtin_amdgcn_s_setprio(1); \
_Pragma("unroll") \
      for (int i = 0; i < 4; ++i) \
_Pragma("unroll") \
        for (int j = 0; j < 4; ++j) \
          acc[i][j] = __builtin_amdgcn_mfma_f32_16x16x32_bf16(af[i], bfv[j], acc[i][j], 0, 0, 0); \
      __builtin_amdgcn_s_setprio(0); \
    }

#define STAGE(CIDX, KT) { stg(ldsb + (CIDX) * 8192, Ab, lda, m0, KT); \
                          stg(ldsb + (CIDX) * 8192 + 4096, Bb, ldb, n0, KT); }

template<int EPI>
__global__ __launch_bounds__(256, 3)
void gemm3(const bf16* __restrict__ A, const bf16* __restrict__ Bm, void* __restrict__ Cout,
           const float* __restrict__ biasCol, const float* __restrict__ biasRow,
           const void* __restrict__ Res, const float* __restrict__ scal2,
           float scale, int K,
           long lda, long ldb, long ldc,
           long sA, long sB, long sC, long sRes, long sBR,
           unsigned gy, unsigned gxy, unsigned nwg)
{
    __shared__ __align__(16) bf16 ldsbuf[3 * 2 * 4096];   // 48 KB
    bf16* ldsb = ldsbuf;

    unsigned id = blockIdx.x;
    {
        const unsigned q = nwg >> 3, r = nwg & 7;
        const unsigned xcd = id & 7, off = id >> 3;
        id = (xcd < r ? xcd * (q + 1) : r * (q + 1) + (xcd - r) * q) + off;
    }
    const unsigned bz = id / gxy;
    const unsigned rem = id - bz * gxy;
    const unsigned bx = rem / gy;        // M-tile: slow (A-panel reuse)
    const unsigned by = rem - bx * gy;   // N-tile: fastest

    const int t = threadIdx.x;
    const int w = t >> 6;
    const int lane = t & 63;
    const int fr = lane & 15;
    const int kg = lane >> 4;
    const int wm = w >> 1, wn = w & 1;
    const long z = bz;
    const long m0 = (long)bx * 128;
    const long n0 = (long)by * 128;
    const bf16* Ab = A + z * sA;
    const bf16* Bb = Bm + z * sB;

    const int srow = w * 16 + (lane >> 2);
    const int gc = (lane & 3) ^ ((lane >> 3) & 3);
    const int slotk = (kg ^ ((fr >> 1) & 3)) * 8;

    auto stg = [&](bf16* dst, const bf16* base, long ld, long rc0, int kt) {
#pragma unroll
        for (int r = 0; r < 2; ++r) {
            const int row = r * 64 + srow;
            const bf16* src = base + (rc0 + row) * ld + kt * 32 + gc * 8;
            gload16(src, dst + row * 32 + (lane & 3) * 8);
        }
    };

    f32x4 acc[4][4] = {};

    const int NT = K >> 5;
    STAGE(0, 0); STAGE(1, 1); STAGE(2, 2);

    int c = 0;
    for (int kt = 0; kt < NT - 2; ++kt) {
        VM8; BAR;
        COMPUTE(c);
        BAR;
        if (kt + 3 < NT) STAGE(c, kt + 3);
        c = (c == 2) ? 0 : c + 1;
    }
    VM4; BAR;
    COMPUTE(c);
    BAR;
    c = (c == 2) ? 0 : c + 1;
    VM0; BAR;
    COMPUTE(c);

    float e0 = 0.f, e1 = 0.f;
    if constexpr (EPI == 8) { e0 = scal2[0]; e1 = scal2[1]; }

#pragma unroll
    for (int i = 0; i < 4; ++i) {
        const long rb = m0 + wm * 64 + i * 16 + kg * 4;
#pragma unroll
        for (int j = 0; j < 4; ++j) {
            const long cc = n0 + wn * 64 + j * 16 + fr;
#pragma unroll
            for (int r = 0; r < 4; ++r) {
                const long rr = rb + r;
                const float v = acc[i][j][r];
                const long idx = z * sC + rr * ldc + cc;
                if constexpr (EPI == 0)      ((bf16*)Cout)[idx] = (bf16)(v + biasCol[z * sBR + cc]);
                else if constexpr (EPI == 1) ((bf16*)Cout)[idx] = (bf16)(v + biasRow[rr]);
                else if constexpr (EPI == 3) ((bf16*)Cout)[idx] = (bf16)v;
                else if constexpr (EPI == 6) ((bf16*)Cout)[idx] = (bf16)__expf(v * scale);
                else if constexpr (EPI == 7) ((bf16*)Cout)[idx] =
                    (bf16)(v * biasRow[z * sBR + rr]
                           + (float)((const bf16*)Res)[z * sRes + rr * ldc + cc] + biasCol[cc]);
                else /* 8 */                 ((bf16*)Cout)[idx] = (bf16)(v * biasCol[z * sBR + cc] * e0 + e1);
            }
        }
    }
}

// ---------------------------------------------------------------------------
// Row inverse-sum of exp-scores: inv[row] = 1 / sum(S[row, :])
// ---------------------------------------------------------------------------
template<int W>
__global__ __launch_bounds__(256)
void rowinv_k(const bf16* __restrict__ S, float* __restrict__ inv)
{
    constexpr int NV = W / 256;
    const long row = blockIdx.x;
    const int t = threadIdx.x;
    const bf16* src = S + row * (long)W + t * NV;
    float s = 0.f;
    if constexpr (NV == 4) { bf16x4 x = *(const bf16x4*)src;
        s = (float)x[0] + (float)x[1] + (float)x[2] + (float)x[3]; }
    else { bf16x2 x = *(const bf16x2*)src; s = (float)x[0] + (float)x[1]; }
#pragma unroll
    for (int o = 32; o > 0; o >>= 1) s += __shfl_xor(s, o);
    __shared__ float red[4];
    const int w = t >> 6, l = t & 63;
    if (l == 0) red[w] = s;
    __syncthreads();
    if (t == 0) inv[row] = 1.f / (red[0] + red[1] + red[2] + red[3]);
}

// ---------------------------------------------------------------------------
template<int OUTBF>
__global__ __launch_bounds__(128)
void ln_rows(const bf16* __restrict__ X, const float* __restrict__ g,
             const float* __restrict__ bta, void* __restrict__ out)
{
    const long row = blockIdx.x;
    const int t = threadIdx.x;
    bf16x4 b4 = *(const bf16x4*)(X + row * 512 + t * 4);
    float v[4] = { (float)b4[0], (float)b4[1], (float)b4[2], (float)b4[3] };
    float s1 = v[0] + v[1] + v[2] + v[3];
    float s2 = v[0]*v[0] + v[1]*v[1] + v[2]*v[2] + v[3]*v[3];
#pragma unroll
    for (int o = 32; o > 0; o >>= 1) { s1 += __shfl_xor(s1, o); s2 += __shfl_xor(s2, o); }
    __shared__ float r1[2], r2[2];
    const int w = t >> 6, l = t & 63;
    if (l == 0) { r1[w] = s1; r2[w] = s2; }
    __syncthreads();
    s1 = r1[0] + r1[1];
    s2 = r2[0] + r2[1];
    const float mean = s1 * (1.f / 512.f);
    const float var  = s2 * (1.f / 512.f) - mean * mean;
    const float rstd = rsqrtf(var + 1e-5f);
    const int c = t * 4;
    if constexpr (OUTBF) {
        bf16x4 o4;
#pragma unroll
        for (int k = 0; k < 4; ++k) o4[k] = (bf16)((v[k] - mean) * rstd * g[c + k] + bta[c + k]);
        *(bf16x4*)((bf16*)out + row * 512 + c) = o4;
    } else {
        f32x4 o4;
#pragma unroll
        for (int k = 0; k < 4; ++k) o4[k] = (v[k] - mean) * rstd * g[c + k] + bta[c + k];
        *(f32x4*)((float*)out + row * 512 + c) = o4;
    }
}

// ---------------------------------------------------------------------------
__global__ __launch_bounds__(256)
void transpose_cvt(const float* __restrict__ x, bf16* __restrict__ Xb, bf16* __restrict__ xt)
{
    __shared__ bf16 tile[32][33];
    const int b = blockIdx.z;
    const int n0 = blockIdx.x * 32, l0 = blockIdx.y * 32;
    const long base = (long)b * N_ID * L_IN;
    const int tx = threadIdx.x, ty = threadIdx.y;
#pragma unroll
    for (int i = ty; i < 32; i += 8) {
        const long idx = base + (long)(n0 + i) * L_IN + l0 + tx;
        const bf16 s = (bf16)x[idx];
        Xb[idx] = s;
        tile[i][tx] = s;
    }
    __syncthreads();
#pragma unroll
    for (int i = ty; i < 32; i += 8)
        xt[base + (long)(l0 + i) * N_ID + n0 + tx] = tile[tx][i];
}

__global__ __launch_bounds__(256)
void transpose512_cvt(const float* __restrict__ a, const float* __restrict__ b,
                      bf16* __restrict__ da, bf16* __restrict__ db)
{
    __shared__ bf16 tile[32][33];
    const float* src = blockIdx.z ? b : a;
    bf16* dst = blockIdx.z ? db : da;
    const int c0 = blockIdx.x * 32, r0 = blockIdx.y * 32;
    const int tx = threadIdx.x, ty = threadIdx.y;
#pragma unroll
    for (int i = ty; i < 32; i += 8)
        tile[i][tx] = (bf16)src[(long)(r0 + i) * 512 + c0 + tx];
    __syncthreads();
#pragma unroll
    for (int i = ty; i < 32; i += 8)
        dst[(long)(c0 + i) * 512 + r0 + tx] = tile[tx][i];
}

struct Ptr6 { const float* s[6]; bf16* d[6]; };

__global__ void cvt_multi(Ptr6 p, int n)
{
    const int j = blockIdx.y;
    const int i = (blockIdx.x * 256 + threadIdx.x) * 4;
    if (i < n) {
        f32x4 v = *(const f32x4*)(p.s[j] + i);
        bf16x4 o; o[0] = (bf16)v[0]; o[1] = (bf16)v[1]; o[2] = (bf16)v[2]; o[3] = (bf16)v[3];
        *(bf16x4*)(p.d[j] + i) = o;
    }
}

__global__ void wo_sum2(const float* __restrict__ a, const float* __restrict__ b,
                        bf16* __restrict__ da, bf16* __restrict__ db)
{
    const int i = blockIdx.x * 256 + threadIdx.x;
    const float* src = blockIdx.y ? b : a;
    bf16* dst = blockIdx.y ? db : da;
    const float* p = src + (long)i * 8;
    float s = 0.f;
#pragma unroll
    for (int h = 0; h < 8; ++h) s += p[h];
    dst[i] = (bf16)s;
}

__global__ __launch_bounds__(64)
void biasfold(const bf16* __restrict__ Ws, const float* __restrict__ bv,
              const float* __restrict__ bo, float* __restrict__ out)
{
    const int o = blockIdx.x;
    float s = 0.f;
    for (int l = threadIdx.x; l < 512; l += 64)
        s += (float)Ws[(long)o * 512 + l] * bv[l];
#pragma unroll
    for (int off = 32; off > 0; off >>= 1) s += __shfl_xor(s, off);
    if (threadIdx.x == 0) out[o] = bo[o] + s;
}

__global__ void concat2(const float* __restrict__ a, const float* __restrict__ b,
                        float* __restrict__ out, int n)
{
    const int i = blockIdx.x * 256 + threadIdx.x;
    if (i < n) { out[i] = a[i]; out[n + i] = b[i]; }
}

__global__ void prep_scal(const float* __restrict__ W1, const float* __restrict__ b1, float* __restrict__ out)
{
    if (threadIdx.x == 0 && blockIdx.x == 0) {
        float s = 0.f;
        for (int h = 0; h < 8; ++h) s += W1[h];
        out[0] = s;
        out[1] = b1[0];
    }
}

// ---------------------------------------------------------------------------
static void launch_gemm(int epi, const bf16* A, const bf16* B, void* C,
                        const float* bc, const float* br, const void* res, const float* sc2,
                        float scale, int M, int N, int K,
                        long lda, long ldb, long ldc,
                        long sA, long sB, long sC, long sRes, long sBR,
                        int batches, hipStream_t st)
{
    const unsigned gx = M / 128, gy = N / 128;
    const unsigned gxy = gx * gy, nwg = gxy * (unsigned)batches;
    dim3 g(nwg), blk(256);
    switch (epi) {
    case 0: gemm3<0><<<g, blk, 0, st>>>(A, B, C, bc, br, res, sc2, scale, K, lda, ldb, ldc, sA, sB, sC, sRes, sBR, gy, gxy, nwg); break;
    case 1: gemm3<1><<<g, blk, 0, st>>>(A, B, C, bc, br, res, sc2, scale, K, lda, ldb, ldc, sA, sB, sC, sRes, sBR, gy, gxy, nwg); break;
    case 3: gemm3<3><<<g, blk, 0, st>>>(A, B, C, bc, br, res, sc2, scale, K, lda, ldb, ldc, sA, sB, sC, sRes, sBR, gy, gxy, nwg); break;
    case 6: gemm3<6><<<g, blk, 0, st>>>(A, B, C, bc, br, res, sc2, scale, K, lda, ldb, ldc, sA, sB, sC, sRes, sBR, gy, gxy, nwg); break;
    case 7: gemm3<7><<<g, blk, 0, st>>>(A, B, C, bc, br, res, sc2, scale, K, lda, ldb, ldc, sA, sB, sC, sRes, sBR, gy, gxy, nwg); break;
    default: gemm3<8><<<g, blk, 0, st>>>(A, B, C, bc, br, res, sc2, scale, K, lda, ldb, ldc, sA, sB, sC, sRes, sBR, gy, gxy, nwg); break;
    }
}

extern "C" void kernel_launch(void* const* d_in, const int* in_sizes, int n_in,
                              void* d_out, int out_size, void* d_ws, size_t ws_size,
                              hipStream_t stream)
{
    (void)in_sizes; (void)n_in; (void)out_size;

    const float* x   = (const float*)d_in[0];
    const float* tWq = (const float*)d_in[1];  const float* tbq = (const float*)d_in[2];
    const float* tWk = (const float*)d_in[3];  const float* tbk = (const float*)d_in[4];
    const float* tWv = (const float*)d_in[5];  const float* tbv = (const float*)d_in[6];
    const float* tWo = (const float*)d_in[7];  const float* tbo = (const float*)d_in[8];
    const float* tg  = (const float*)d_in[9];  const float* tb  = (const float*)d_in[10];
    const float* cWq = (const float*)d_in[11]; const float* cbq = (const float*)d_in[12];
    const float* cWk = (const float*)d_in[13]; const float* cbk = (const float*)d_in[14];
    const float* cWv = (const float*)d_in[15]; const float* cbv = (const float*)d_in[16];
    const float* cWo = (const float*)d_in[17]; const float* cbo = (const float*)d_in[18];
    const float* cg  = (const float*)d_in[19]; const float* cb  = (const float*)d_in[20];
    const float* sWq = (const float*)d_in[21]; const float* sbq = (const float*)d_in[22];
    const float* sWk = (const float*)d_in[23]; const float* sbk = (const float*)d_in[24];
    const float* sWv = (const float*)d_in[25]; const float* sbv = (const float*)d_in[26];
    const float* sW1 = (const float*)d_in[27]; const float* sb1 = (const float*)d_in[28];

    char* p = (char*)d_ws;
    auto alloc = [&](size_t bytes) -> char* {
        char* r = p; p += (bytes + 255) & ~(size_t)255; return r;
    };

    bf16* WqkT = (bf16*)alloc(2 * 262144 * 2);   // [Wq|Wk] time
    bf16* WqC  = (bf16*)alloc(262144 * 2);  bf16* WkC = (bf16*)alloc(262144 * 2);  // adjacent
    bf16* WqkS = (bf16*)alloc(2 * 1048576 * 2);
    bf16* WvS  = (bf16*)alloc(1048576 * 2);
    bf16* WsT  = (bf16*)alloc(262144 * 2);  bf16* WsC = (bf16*)alloc(262144 * 2);  // adjacent
    bf16* WvTrT = (bf16*)alloc(262144 * 2); bf16* WvTrC = (bf16*)alloc(262144 * 2); // adjacent
    bf16* WvWT = (bf16*)alloc(262144 * 2);  bf16* WvWC = (bf16*)alloc(262144 * 2);  // adjacent
    float* scal = (float*)alloc(256);
    float* bqkT = (float*)alloc(1024 * 4);
    float* sbqk = (float*)alloc(2048 * 4);
    float* bqkC = (float*)alloc(1024 * 4);
    float* biasT = (float*)alloc(512 * 4);
    float* biasC = (float*)alloc(512 * 4);

    const size_t ACT_B = (size_t)ACT_E * 2;
    bf16* bufQK = (bf16*)alloc(2 * ACT_B);  // [32768,1024] or [16384,2048]
    bf16* Xb    = (bf16*)alloc(ACT_B);      // reused as SO after stage T
    bf16* TO    = (bf16*)alloc(ACT_B);      // adjacent to Xb (batched C-proj)
    bf16* xt    = (bf16*)alloc(ACT_B);
    bf16* bufV  = (bf16*)alloc(ACT_B);      // VW^T (time/cross) or Vs^T (space)
    bf16* PL    = (bf16*)alloc(ACT_B);      // preLN scratch
    float* Rbuf = (float*)alloc(BATCH * 1024 * 4);  // row inverse-sums

    size_t used = (size_t)(p - (char*)d_ws);
    int CB = 32;
    while (CB > 1 && used + (size_t)CB * 2097152ULL + 4096 > ws_size) CB >>= 1;
    bf16* Sbuf = (bf16*)alloc((size_t)CB * 2097152ULL);
    bf16* Pbuf = Sbuf;   // exp-scores, unnormalized

    const float rsc_t = 0.08838834764831845f;  // 1/sqrt(1024/8)
    const float rsc_s = 0.125f;                // 1/sqrt(512/8)

    // ---- prep ----
    Ptr6 smallW = {};
    smallW.s[0] = tWq; smallW.s[1] = tWk; smallW.s[2] = cWq; smallW.s[3] = cWk;
    smallW.d[0] = WqkT; smallW.d[1] = WqkT + 262144; smallW.d[2] = WqC; smallW.d[3] = WkC;
    cvt_multi<<<dim3(256, 4), dim3(256), 0, stream>>>(smallW, 262144);
    Ptr6 bigW = {};
    bigW.s[0] = sWq;  bigW.s[1] = sWk;            bigW.s[2] = sWv;
    bigW.d[0] = WqkS; bigW.d[1] = WqkS + 1048576; bigW.d[2] = WvS;
    cvt_multi<<<dim3(1024, 3), dim3(256), 0, stream>>>(bigW, 1048576);
    wo_sum2<<<dim3(1024, 2), dim3(256), 0, stream>>>(tWo, cWo, WsT, WsC);
    transpose512_cvt<<<dim3(16, 16, 2), dim3(32, 8), 0, stream>>>(tWv, cWv, WvTrT, WvTrC);
    biasfold<<<dim3(512), dim3(64), 0, stream>>>(WsT, tbv, tbo, biasT);
    biasfold<<<dim3(512), dim3(64), 0, stream>>>(WsC, cbv, cbo, biasC);
    // WvW = Wsum @ Wv for T and C in one batched dispatch
    launch_gemm(3, WsT, WvTrT, WvWT, nullptr, nullptr, nullptr, nullptr, 0.f,
                512, 512, 512, 512, 512, 512, 262144, 262144, 262144, 0, 0, 2, stream);
    concat2<<<dim3(2), dim3(256), 0, stream>>>(tbq, tbk, bqkT, 512);
    concat2<<<dim3(4), dim3(256), 0, stream>>>(sbq, sbk, sbqk, 1024);
    concat2<<<dim3(2), dim3(256), 0, stream>>>(cbq, cbk, bqkC, 512);
    prep_scal<<<dim3(1), dim3(64), 0, stream>>>(sW1, sb1, scal);
    transpose_cvt<<<dim3(32, 16, BATCH), dim3(32, 8), 0, stream>>>(x, Xb, xt);

    // time/cross attention, no-max softmax fused:
    // S=exp(QK^T*rsc) -> rowinv -> preLN = (P@VW^T)*rowinv + Res + bias'
    auto attn_tc = [&](const bf16* ResP, const float* biasP) {
        for (int c0 = 0; c0 < BATCH; c0 += CB) {
            const long offQ = (long)c0 * S_TT;
            const long offV = (long)c0 * S_NL;
            launch_gemm(6, bufQK + offQ, bufQK + 512 + offQ, Sbuf, nullptr, nullptr, nullptr, nullptr, rsc_t,
                        1024, 1024, 512, 1024, 1024, 1024, S_TT, S_TT, S_TT, 0, 0, CB, stream);
            rowinv_k<1024><<<dim3(CB * 1024), dim3(256), 0, stream>>>(Sbuf, Rbuf);
            launch_gemm(7, Pbuf, bufV + offV, PL + offV, biasP, Rbuf, ResP + offV, nullptr, 0.f,
                        1024, 512, 1024, 1024, 1024, 512, S_TT, S_NL, S_NL, S_NL, 1024, CB, stream);
        }
    };

    // ==== Stage T (time de_att) ====
    launch_gemm(0, Xb, WqkT, bufQK, bqkT, nullptr, nullptr, nullptr, 0.f,
                32768, 1024, 512, 512, 512, 1024, 0, 0, 0, 0, 0, 1, stream);
    launch_gemm(3, WvWT, Xb, bufV, nullptr, nullptr, nullptr, nullptr, 0.f,
                512, 1024, 512, 512, 512, 1024, 0, S_NL, S_NL, 0, 0, BATCH, stream);
    attn_tc(Xb, biasT);
    ln_rows<1><<<dim3(32768), dim3(128), 0, stream>>>(PL, tg, tb, TO);

    // ==== Stage S (space attention) ====
    bf16* SOp = Xb;   // Xb dead after stage T -> space_out
    launch_gemm(0, xt, WqkS, bufQK, sbqk, nullptr, nullptr, nullptr, 0.f,
                16384, 2048, 1024, 1024, 1024, 2048, 0, 0, 0, 0, 0, 1, stream);
    launch_gemm(1, WvS, xt, bufV, nullptr, sbv, nullptr, nullptr, 0.f,
                1024, 512, 1024, 1024, 1024, 512, 0, S_NL, S_NL, 0, 0, BATCH, stream);
    for (int c0 = 0; c0 < BATCH; c0 += CB) {
        const long offQ = (long)c0 * S_TT;
        const long offV = (long)c0 * S_NL;
        launch_gemm(6, bufQK + offQ, bufQK + 1024 + offQ, Sbuf, nullptr, nullptr, nullptr, nullptr, rsc_s,
                    512, 512, 1024, 2048, 2048, 512, S_TT, S_TT, (long)L_IN * L_IN, 0, 0, CB, stream);
        rowinv_k<512><<<dim3(CB * 512), dim3(256), 0, stream>>>(Sbuf, Rbuf);
        // line^T scaled: C[node, l] = (sum_k Vs[node,k] P[l,k]) * colInv[l] * scal0 + scal1
        launch_gemm(8, bufV + offV, Pbuf, SOp + offV, Rbuf, nullptr, nullptr, scal, 0.f,
                    1024, 512, 512, 512, 512, 512, S_NL, (long)L_IN * L_IN, S_NL, 0, 512, CB, stream);
    }

    // ==== Stage C (cross de_att) ====
    // merged Q/K projection: z=0 A=SOp(Xb) B=WqC -> cols 0..511; z=1 A=TO B=WkC -> cols 512..1023
    launch_gemm(0, Xb, WqC, bufQK, bqkC, nullptr, nullptr, nullptr, 0.f,
                32768, 512, 512, 512, 512, 1024, ACT_E, 262144, 512, 0, 512, 2, stream);
    launch_gemm(3, WvWC, TO, bufV, nullptr, nullptr, nullptr, nullptr, 0.f,
                512, 1024, 512, 512, 512, 1024, 0, S_NL, S_NL, 0, 0, BATCH, stream);
    attn_tc(TO, biasC);
    ln_rows<0><<<dim3(32768), dim3(128), 0, stream>>>(PL, cg, cb, d_out);
}

// Round 11
// 775.085 us; speedup vs baseline: 1.2159x; 1.0254x over previous
//
#include <hip/hip_runtime.h>
#include <hip/hip_bf16.h>

typedef __bf16 bf16;
typedef __bf16 bf16x8 __attribute__((ext_vector_type(8)));
typedef __bf16 bf16x4 __attribute__((ext_vector_type(4)));
typedef __bf16 bf16x2 __attribute__((ext_vector_type(2)));
typedef float f32x4 __attribute__((ext_vector_type(4)));

#define BATCH 32
#define N_ID 1024
#define L_IN 512

static const long ACT_E = (long)BATCH * N_ID * L_IN;   // 16,777,216
static const long S_NL  = (long)N_ID * L_IN;           // 524288
static const long S_TT  = (long)N_ID * N_ID;           // 1048576

__device__ __forceinline__ void gload16(const bf16* g, bf16* l)
{
    __builtin_amdgcn_global_load_lds((__attribute__((address_space(1))) void*)g,
                                     (__attribute__((address_space(3))) void*)l, 16, 0, 0);
}

// ---------------------------------------------------------------------------
// 128x128 BK=32 triple-buffered counted-vmcnt NT GEMM (3 blocks/CU).
// C[m,n] = sum_k A[m,k]*B[n,k]; strides lda/ldb/ldc decoupled.
// EPI: 0 bf16=acc+biasCol[z*sBR+cc]; 1 bf16=acc+biasRow[m]; 3 bf16=acc;
//      6 bf16=exp2(acc*scale), atomic rowsum -> biasRow[z*sBR+rr]  (QK^T)
//      7 bf16=acc/Rsum[z*sBR+rr]+ResBF16+biasCol[cc]   (time/cross PV)
//      8 bf16=acc/Rsum[z*sBR+cc]*scal2[0]+scal2[1]     (space PV)
// ---------------------------------------------------------------------------
#define VM8 asm volatile("s_waitcnt vmcnt(8)" ::: "memory")
#define VM4 asm volatile("s_waitcnt vmcnt(4)" ::: "memory")
#define VM0 asm volatile("s_waitcnt vmcnt(0)" ::: "memory")
#define BAR __builtin_amdgcn_s_barrier()

#define COMPUTE(CIDX) \
    { \
      const bf16* pa = ldsb + (CIDX) * 8192; \
      const bf16* pb = pa + 4096; \
      bf16x8 af[4], bfv[4]; \
_Pragma("unroll") \
      for (int i = 0; i < 4; ++i) \
        af[i] = *(const bf16x8*)(pa + (wm * 64 + i * 16 + fr) * 32 + slotk); \
_Pragma("unroll") \
      for (int j = 0; j < 4; ++j) \
        bfv[j] = *(const bf16x8*)(pb + (wn * 64 + j * 16 + fr) * 32 + slotk); \
      __builtin_amdgcn_s_setprio(1); \
_Pragma("unroll") \
      for (int i = 0; i < 4; ++i) \
_Pragma("unroll") \
        for (int j = 0; j < 4; ++j) \
          acc[i][j] = __builtin_amdgcn_mfma_f32_16x16x32_bf16(af[i], bfv[j], acc[i][j], 0, 0, 0); \
      __builtin_amdgcn_s_setprio(0); \
    }

#define STAGE(CIDX, KT) { stg(ldsb + (CIDX) * 8192, Ab, lda, m0, KT); \
                          stg(ldsb + (CIDX) * 8192 + 4096, Bb, ldb, n0, KT); }

template<int EPI>
__global__ __launch_bounds__(256, 3)
void gemm3(const bf16* __restrict__ A, const bf16* __restrict__ Bm, void* __restrict__ Cout,
           const float* __restrict__ biasCol, const float* __restrict__ biasRow,
           const void* __restrict__ Res, const float* __restrict__ scal2,
           float scale, int K,
           long lda, long ldb, long ldc,
           long sA, long sB, long sC, long sRes, long sBR,
           unsigned gy, unsigned gxy, unsigned nwg)
{
    __shared__ __align__(16) bf16 ldsbuf[3 * 2 * 4096];   // 48 KB
    bf16* ldsb = ldsbuf;

    unsigned id = blockIdx.x;
    {
        const unsigned q = nwg >> 3, r = nwg & 7;
        const unsigned xcd = id & 7, off = id >> 3;
        id = (xcd < r ? xcd * (q + 1) : r * (q + 1) + (xcd - r) * q) + off;
    }
    const unsigned bz = id / gxy;
    const unsigned rem = id - bz * gxy;
    const unsigned bx = rem / gy;        // M-tile: slow (A-panel reuse)
    const unsigned by = rem - bx * gy;   // N-tile: fastest

    const int t = threadIdx.x;
    const int w = t >> 6;
    const int lane = t & 63;
    const int fr = lane & 15;
    const int kg = lane >> 4;
    const int wm = w >> 1, wn = w & 1;
    const long z = bz;
    const long m0 = (long)bx * 128;
    const long n0 = (long)by * 128;
    const bf16* Ab = A + z * sA;
    const bf16* Bb = Bm + z * sB;

    const int srow = w * 16 + (lane >> 2);
    const int gc = (lane & 3) ^ ((lane >> 3) & 3);
    const int slotk = (kg ^ ((fr >> 1) & 3)) * 8;

    auto stg = [&](bf16* dst, const bf16* base, long ld, long rc0, int kt) {
#pragma unroll
        for (int r = 0; r < 2; ++r) {
            const int row = r * 64 + srow;
            const bf16* src = base + (rc0 + row) * ld + kt * 32 + gc * 8;
            gload16(src, dst + row * 32 + (lane & 3) * 8);
        }
    };

    f32x4 acc[4][4] = {};

    const int NT = K >> 5;
    STAGE(0, 0); STAGE(1, 1); STAGE(2, 2);

    int c = 0;
    for (int kt = 0; kt < NT - 2; ++kt) {
        VM8; BAR;
        COMPUTE(c);
        BAR;
        if (kt + 3 < NT) STAGE(c, kt + 3);
        c = (c == 2) ? 0 : c + 1;
    }
    VM4; BAR;
    COMPUTE(c);
    BAR;
    c = (c == 2) ? 0 : c + 1;
    VM0; BAR;
    COMPUTE(c);

    float e0 = 0.f, e1 = 0.f;
    if constexpr (EPI == 8) { e0 = scal2[0]; e1 = scal2[1]; }

    float rs[16];
    if constexpr (EPI == 6) {
#pragma unroll
        for (int vv = 0; vv < 16; ++vv) rs[vv] = 0.f;
    }

#pragma unroll
    for (int i = 0; i < 4; ++i) {
        const long rb = m0 + wm * 64 + i * 16 + kg * 4;
#pragma unroll
        for (int j = 0; j < 4; ++j) {
            const long cc = n0 + wn * 64 + j * 16 + fr;
            float cinv = 0.f;
            if constexpr (EPI == 8) cinv = 1.f / biasCol[z * sBR + cc];
#pragma unroll
            for (int r = 0; r < 4; ++r) {
                const long rr = rb + r;
                const float v = acc[i][j][r];
                const long idx = z * sC + rr * ldc + cc;
                if constexpr (EPI == 0)      ((bf16*)Cout)[idx] = (bf16)(v + biasCol[z * sBR + cc]);
                else if constexpr (EPI == 1) ((bf16*)Cout)[idx] = (bf16)(v + biasRow[rr]);
                else if constexpr (EPI == 3) ((bf16*)Cout)[idx] = (bf16)v;
                else if constexpr (EPI == 6) {
                    const float e = __builtin_amdgcn_exp2f(v * scale);
                    ((bf16*)Cout)[idx] = (bf16)e;
                    rs[i * 4 + r] += e;
                }
                else if constexpr (EPI == 7) ((bf16*)Cout)[idx] =
                    (bf16)(v * (1.f / biasRow[z * sBR + rr])
                           + (float)((const bf16*)Res)[z * sRes + rr * ldc + cc] + biasCol[cc]);
                else /* 8 */                 ((bf16*)Cout)[idx] = (bf16)(v * cinv * e0 + e1);
            }
        }
    }

    if constexpr (EPI == 6) {
        // butterfly over fr lanes (lane bits 0..3): each wave's 64-col partial
#pragma unroll
        for (int vv = 0; vv < 16; ++vv) {
            rs[vv] += __shfl_xor(rs[vv], 1);
            rs[vv] += __shfl_xor(rs[vv], 2);
            rs[vv] += __shfl_xor(rs[vv], 4);
            rs[vv] += __shfl_xor(rs[vv], 8);
        }
        if (fr == 0) {
            float* Rs = (float*)biasRow + z * sBR;
#pragma unroll
            for (int i = 0; i < 4; ++i)
#pragma unroll
                for (int r = 0; r < 4; ++r) {
                    const long rr = m0 + wm * 64 + i * 16 + kg * 4 + r;
                    atomicAdd(Rs + rr, rs[i * 4 + r]);
                }
        }
    }
}

// ---------------------------------------------------------------------------
template<int OUTBF>
__global__ __launch_bounds__(128)
void ln_rows(const bf16* __restrict__ X, const float* __restrict__ g,
             const float* __restrict__ bta, void* __restrict__ out)
{
    const long row = blockIdx.x;
    const int t = threadIdx.x;
    bf16x4 b4 = *(const bf16x4*)(X + row * 512 + t * 4);
    float v[4] = { (float)b4[0], (float)b4[1], (float)b4[2], (float)b4[3] };
    float s1 = v[0] + v[1] + v[2] + v[3];
    float s2 = v[0]*v[0] + v[1]*v[1] + v[2]*v[2] + v[3]*v[3];
#pragma unroll
    for (int o = 32; o > 0; o >>= 1) { s1 += __shfl_xor(s1, o); s2 += __shfl_xor(s2, o); }
    __shared__ float r1[2], r2[2];
    const int w = t >> 6, l = t & 63;
    if (l == 0) { r1[w] = s1; r2[w] = s2; }
    __syncthreads();
    s1 = r1[0] + r1[1];
    s2 = r2[0] + r2[1];
    const float mean = s1 * (1.f / 512.f);
    const float var  = s2 * (1.f / 512.f) - mean * mean;
    const float rstd = rsqrtf(var + 1e-5f);
    const int c = t * 4;
    if constexpr (OUTBF) {
        bf16x4 o4;
#pragma unroll
        for (int k = 0; k < 4; ++k) o4[k] = (bf16)((v[k] - mean) * rstd * g[c + k] + bta[c + k]);
        *(bf16x4*)((bf16*)out + row * 512 + c) = o4;
    } else {
        f32x4 o4;
#pragma unroll
        for (int k = 0; k < 4; ++k) o4[k] = (v[k] - mean) * rstd * g[c + k] + bta[c + k];
        *(f32x4*)((float*)out + row * 512 + c) = o4;
    }
}

// ---------------------------------------------------------------------------
__global__ __launch_bounds__(256)
void transpose_cvt(const float* __restrict__ x, bf16* __restrict__ Xb, bf16* __restrict__ xt)
{
    __shared__ bf16 tile[32][33];
    const int b = blockIdx.z;
    const int n0 = blockIdx.x * 32, l0 = blockIdx.y * 32;
    const long base = (long)b * N_ID * L_IN;
    const int tx = threadIdx.x, ty = threadIdx.y;
#pragma unroll
    for (int i = ty; i < 32; i += 8) {
        const long idx = base + (long)(n0 + i) * L_IN + l0 + tx;
        const bf16 s = (bf16)x[idx];
        Xb[idx] = s;
        tile[i][tx] = s;
    }
    __syncthreads();
#pragma unroll
    for (int i = ty; i < 32; i += 8)
        xt[base + (long)(l0 + i) * N_ID + n0 + tx] = tile[tx][i];
}

__global__ __launch_bounds__(256)
void transpose512_cvt(const float* __restrict__ a, const float* __restrict__ b,
                      bf16* __restrict__ da, bf16* __restrict__ db)
{
    __shared__ bf16 tile[32][33];
    const float* src = blockIdx.z ? b : a;
    bf16* dst = blockIdx.z ? db : da;
    const int c0 = blockIdx.x * 32, r0 = blockIdx.y * 32;
    const int tx = threadIdx.x, ty = threadIdx.y;
#pragma unroll
    for (int i = ty; i < 32; i += 8)
        tile[i][tx] = (bf16)src[(long)(r0 + i) * 512 + c0 + tx];
    __syncthreads();
#pragma unroll
    for (int i = ty; i < 32; i += 8)
        dst[(long)(c0 + i) * 512 + r0 + tx] = tile[tx][i];
}

struct Ptr6 { const float* s[6]; bf16* d[6]; };

__global__ void cvt_multi(Ptr6 p, int n)
{
    const int j = blockIdx.y;
    const int i = (blockIdx.x * 256 + threadIdx.x) * 4;
    if (i < n) {
        f32x4 v = *(const f32x4*)(p.s[j] + i);
        bf16x4 o; o[0] = (bf16)v[0]; o[1] = (bf16)v[1]; o[2] = (bf16)v[2]; o[3] = (bf16)v[3];
        *(bf16x4*)(p.d[j] + i) = o;
    }
}

__global__ void wo_sum2(const float* __restrict__ a, const float* __restrict__ b,
                        bf16* __restrict__ da, bf16* __restrict__ db)
{
    const int i = blockIdx.x * 256 + threadIdx.x;
    const float* src = blockIdx.y ? b : a;
    bf16* dst = blockIdx.y ? db : da;
    const float* p = src + (long)i * 8;
    float s = 0.f;
#pragma unroll
    for (int h = 0; h < 8; ++h) s += p[h];
    dst[i] = (bf16)s;
}

// two biasfolds batched via y: out[o] = bo[o] + sum_l Ws[o,l]*bv[l]
__global__ __launch_bounds__(64)
void biasfold2(const bf16* __restrict__ WsA, const float* __restrict__ bvA, const float* __restrict__ boA, float* __restrict__ outA,
               const bf16* __restrict__ WsB, const float* __restrict__ bvB, const float* __restrict__ boB, float* __restrict__ outB)
{
    const bf16* Ws = blockIdx.y ? WsB : WsA;
    const float* bv = blockIdx.y ? bvB : bvA;
    const float* bo = blockIdx.y ? boB : boA;
    float* out = blockIdx.y ? outB : outA;
    const int o = blockIdx.x;
    float s = 0.f;
    for (int l = threadIdx.x; l < 512; l += 64)
        s += (float)Ws[(long)o * 512 + l] * bv[l];
#pragma unroll
    for (int off = 32; off > 0; off >>= 1) s += __shfl_xor(s, off);
    if (threadIdx.x == 0) out[o] = bo[o] + s;
}

// all tiny bias preps in one launch (jobs via y)
__global__ void prep_misc(const float* tbq, const float* tbk, float* bqkT,
                          const float* sbq, const float* sbk, float* sbqk,
                          const float* cbq, const float* cbk, float* bqkC,
                          const float* sW1, const float* sb1, float* scal)
{
    const int i = blockIdx.x * 256 + threadIdx.x;
    switch (blockIdx.y) {
    case 0: if (i < 512) { bqkT[i] = tbq[i]; bqkT[512 + i] = tbk[i]; } break;
    case 1: if (i < 1024) { sbqk[i] = sbq[i]; sbqk[1024 + i] = sbk[i]; } break;
    case 2: if (i < 512) { bqkC[i] = cbq[i]; bqkC[512 + i] = cbk[i]; } break;
    default:
        if (i == 0) {
            float s = 0.f;
            for (int h = 0; h < 8; ++h) s += sW1[h];
            scal[0] = s; scal[1] = sb1[0];
        }
    }
}

// ---------------------------------------------------------------------------
static void launch_gemm(int epi, const bf16* A, const bf16* B, void* C,
                        const float* bc, const float* br, const void* res, const float* sc2,
                        float scale, int M, int N, int K,
                        long lda, long ldb, long ldc,
                        long sA, long sB, long sC, long sRes, long sBR,
                        int batches, hipStream_t st)
{
    const unsigned gx = M / 128, gy = N / 128;
    const unsigned gxy = gx * gy, nwg = gxy * (unsigned)batches;
    dim3 g(nwg), blk(256);
    switch (epi) {
    case 0: gemm3<0><<<g, blk, 0, st>>>(A, B, C, bc, br, res, sc2, scale, K, lda, ldb, ldc, sA, sB, sC, sRes, sBR, gy, gxy, nwg); break;
    case 1: gemm3<1><<<g, blk, 0, st>>>(A, B, C, bc, br, res, sc2, scale, K, lda, ldb, ldc, sA, sB, sC, sRes, sBR, gy, gxy, nwg); break;
    case 3: gemm3<3><<<g, blk, 0, st>>>(A, B, C, bc, br, res, sc2, scale, K, lda, ldb, ldc, sA, sB, sC, sRes, sBR, gy, gxy, nwg); break;
    case 6: gemm3<6><<<g, blk, 0, st>>>(A, B, C, bc, br, res, sc2, scale, K, lda, ldb, ldc, sA, sB, sC, sRes, sBR, gy, gxy, nwg); break;
    case 7: gemm3<7><<<g, blk, 0, st>>>(A, B, C, bc, br, res, sc2, scale, K, lda, ldb, ldc, sA, sB, sC, sRes, sBR, gy, gxy, nwg); break;
    default: gemm3<8><<<g, blk, 0, st>>>(A, B, C, bc, br, res, sc2, scale, K, lda, ldb, ldc, sA, sB, sC, sRes, sBR, gy, gxy, nwg); break;
    }
}

extern "C" void kernel_launch(void* const* d_in, const int* in_sizes, int n_in,
                              void* d_out, int out_size, void* d_ws, size_t ws_size,
                              hipStream_t stream)
{
    (void)in_sizes; (void)n_in; (void)out_size;

    const float* x   = (const float*)d_in[0];
    const float* tWq = (const float*)d_in[1];  const float* tbq = (const float*)d_in[2];
    const float* tWk = (const float*)d_in[3];  const float* tbk = (const float*)d_in[4];
    const float* tWv = (const float*)d_in[5];  const float* tbv = (const float*)d_in[6];
    const float* tWo = (const float*)d_in[7];  const float* tbo = (const float*)d_in[8];
    const float* tg  = (const float*)d_in[9];  const float* tb  = (const float*)d_in[10];
    const float* cWq = (const float*)d_in[11]; const float* cbq = (const float*)d_in[12];
    const float* cWk = (const float*)d_in[13]; const float* cbk = (const float*)d_in[14];
    const float* cWv = (const float*)d_in[15]; const float* cbv = (const float*)d_in[16];
    const float* cWo = (const float*)d_in[17]; const float* cbo = (const float*)d_in[18];
    const float* cg  = (const float*)d_in[19]; const float* cb  = (const float*)d_in[20];
    const float* sWq = (const float*)d_in[21]; const float* sbq = (const float*)d_in[22];
    const float* sWk = (const float*)d_in[23]; const float* sbk = (const float*)d_in[24];
    const float* sWv = (const float*)d_in[25]; const float* sbv = (const float*)d_in[26];
    const float* sW1 = (const float*)d_in[27]; const float* sb1 = (const float*)d_in[28];

    char* p = (char*)d_ws;
    auto alloc = [&](size_t bytes) -> char* {
        char* r = p; p += (bytes + 255) & ~(size_t)255; return r;
    };

    bf16* WqkT = (bf16*)alloc(2 * 262144 * 2);   // [Wq|Wk] time
    bf16* WqC  = (bf16*)alloc(262144 * 2);  bf16* WkC = (bf16*)alloc(262144 * 2);  // adjacent
    bf16* WqkS = (bf16*)alloc(2 * 1048576 * 2);
    bf16* WvS  = (bf16*)alloc(1048576 * 2);
    bf16* WsT  = (bf16*)alloc(262144 * 2);  bf16* WsC = (bf16*)alloc(262144 * 2);
    bf16* WvTrT = (bf16*)alloc(262144 * 2); bf16* WvTrC = (bf16*)alloc(262144 * 2);
    bf16* WvWT = (bf16*)alloc(262144 * 2);  bf16* WvWC = (bf16*)alloc(262144 * 2);  // adjacent
    float* scal = (float*)alloc(256);
    float* bqkT = (float*)alloc(1024 * 4);
    float* sbqk = (float*)alloc(2048 * 4);
    float* bqkC = (float*)alloc(1024 * 4);
    float* biasT = (float*)alloc(512 * 4);
    float* biasC = (float*)alloc(512 * 4);

    const size_t ACT_B = (size_t)ACT_E * 2;
    bf16* bufQK = (bf16*)alloc(2 * ACT_B);  // [32768,1024] or [16384,2048]
    bf16* Xb    = (bf16*)alloc(ACT_B);      // reused as SO after stage T
    bf16* TO    = (bf16*)alloc(ACT_B);      // adjacent to Xb (batched C-proj)
    bf16* xt    = (bf16*)alloc(ACT_B);
    bf16* bufV  = (bf16*)alloc(ACT_B);      // VW^T (time/cross) or Vs^T (space)
    bf16* PL    = (bf16*)alloc(ACT_B);      // preLN scratch
    float* Rbuf = (float*)alloc(BATCH * 1024 * 4);  // row sums (atomic-accumulated)

    size_t used = (size_t)(p - (char*)d_ws);
    int CB = 32;
    while (CB > 1 && used + (size_t)CB * 2097152ULL + 4096 > ws_size) CB >>= 1;
    bf16* Sbuf = (bf16*)alloc((size_t)CB * 2097152ULL);
    bf16* Pbuf = Sbuf;   // exp-scores, unnormalized

    const float L2E = 1.4426950408889634f;
    const float rsc_t2 = 0.08838834764831845f * L2E;  // (1/sqrt(1024/8))*log2(e)
    const float rsc_s2 = 0.125f * L2E;                // (1/sqrt(512/8))*log2(e)

    // ---- prep ----
    Ptr6 smallW = {};
    smallW.s[0] = tWq; smallW.s[1] = tWk; smallW.s[2] = cWq; smallW.s[3] = cWk;
    smallW.d[0] = WqkT; smallW.d[1] = WqkT + 262144; smallW.d[2] = WqC; smallW.d[3] = WkC;
    cvt_multi<<<dim3(256, 4), dim3(256), 0, stream>>>(smallW, 262144);
    Ptr6 bigW = {};
    bigW.s[0] = sWq;  bigW.s[1] = sWk;            bigW.s[2] = sWv;
    bigW.d[0] = WqkS; bigW.d[1] = WqkS + 1048576; bigW.d[2] = WvS;
    cvt_multi<<<dim3(1024, 3), dim3(256), 0, stream>>>(bigW, 1048576);
    wo_sum2<<<dim3(1024, 2), dim3(256), 0, stream>>>(tWo, cWo, WsT, WsC);
    transpose512_cvt<<<dim3(16, 16, 2), dim3(32, 8), 0, stream>>>(tWv, cWv, WvTrT, WvTrC);
    biasfold2<<<dim3(512, 2), dim3(64), 0, stream>>>(WsT, tbv, tbo, biasT, WsC, cbv, cbo, biasC);
    launch_gemm(3, WsT, WvTrT, WvWT, nullptr, nullptr, nullptr, nullptr, 0.f,
                512, 512, 512, 512, 512, 512, 262144, 262144, 262144, 0, 0, 2, stream);
    prep_misc<<<dim3(4, 4), dim3(256), 0, stream>>>(tbq, tbk, bqkT, sbq, sbk, sbqk,
                                                    cbq, cbk, bqkC, sW1, sb1, scal);
    transpose_cvt<<<dim3(32, 16, BATCH), dim3(32, 8), 0, stream>>>(x, Xb, xt);

    // time/cross attention, rowsum fused into QK^T epilogue:
    // S=exp2(QK^T*rsc*log2e) [+atomic rowsum] -> preLN = (P@VW^T)/Rsum + Res + bias'
    auto attn_tc = [&](const bf16* ResP, const float* biasP) {
        for (int c0 = 0; c0 < BATCH; c0 += CB) {
            const long offQ = (long)c0 * S_TT;
            const long offV = (long)c0 * S_NL;
            hipMemsetAsync(Rbuf, 0, (size_t)CB * 1024 * 4, stream);
            launch_gemm(6, bufQK + offQ, bufQK + 512 + offQ, Sbuf, nullptr, Rbuf, nullptr, nullptr, rsc_t2,
                        1024, 1024, 512, 1024, 1024, 1024, S_TT, S_TT, S_TT, 0, 1024, CB, stream);
            launch_gemm(7, Pbuf, bufV + offV, PL + offV, biasP, Rbuf, ResP + offV, nullptr, 0.f,
                        1024, 512, 1024, 1024, 1024, 512, S_TT, S_NL, S_NL, S_NL, 1024, CB, stream);
        }
    };

    // ==== Stage T (time de_att) ====
    launch_gemm(0, Xb, WqkT, bufQK, bqkT, nullptr, nullptr, nullptr, 0.f,
                32768, 1024, 512, 512, 512, 1024, 0, 0, 0, 0, 0, 1, stream);
    launch_gemm(3, WvWT, Xb, bufV, nullptr, nullptr, nullptr, nullptr, 0.f,
                512, 1024, 512, 512, 512, 1024, 0, S_NL, S_NL, 0, 0, BATCH, stream);
    attn_tc(Xb, biasT);
    ln_rows<1><<<dim3(32768), dim3(128), 0, stream>>>(PL, tg, tb, TO);

    // ==== Stage S (space attention) ====
    bf16* SOp = Xb;   // Xb dead after stage T -> space_out
    launch_gemm(0, xt, WqkS, bufQK, sbqk, nullptr, nullptr, nullptr, 0.f,
                16384, 2048, 1024, 1024, 1024, 2048, 0, 0, 0, 0, 0, 1, stream);
    launch_gemm(1, WvS, xt, bufV, nullptr, sbv, nullptr, nullptr, 0.f,
                1024, 512, 1024, 1024, 1024, 512, 0, S_NL, S_NL, 0, 0, BATCH, stream);
    for (int c0 = 0; c0 < BATCH; c0 += CB) {
        const long offQ = (long)c0 * S_TT;
        const long offV = (long)c0 * S_NL;
        hipMemsetAsync(Rbuf, 0, (size_t)CB * 512 * 4, stream);
        launch_gemm(6, bufQK + offQ, bufQK + 1024 + offQ, Sbuf, nullptr, Rbuf, nullptr, nullptr, rsc_s2,
                    512, 512, 1024, 2048, 2048, 512, S_TT, S_TT, (long)L_IN * L_IN, 0, 512, CB, stream);
        launch_gemm(8, bufV + offV, Pbuf, SOp + offV, Rbuf, nullptr, nullptr, scal, 0.f,
                    1024, 512, 512, 512, 512, 512, S_NL, (long)L_IN * L_IN, S_NL, 0, 512, CB, stream);
    }

    // ==== Stage C (cross de_att) ====
    launch_gemm(0, Xb, WqC, bufQK, bqkC, nullptr, nullptr, nullptr, 0.f,
                32768, 512, 512, 512, 512, 1024, ACT_E, 262144, 512, 0, 512, 2, stream);
    launch_gemm(3, WvWC, TO, bufV, nullptr, nullptr, nullptr, nullptr, 0.f,
                512, 1024, 512, 512, 512, 1024, 0, S_NL, S_NL, 0, 0, BATCH, stream);
    attn_tc(TO, biasC);
    ln_rows<0><<<dim3(32768), dim3(128), 0, stream>>>(PL, cg, cb, d_out);
}

// Round 12
// 649.864 us; speedup vs baseline: 1.4501x; 1.1927x over previous
//
#include <hip/hip_runtime.h>
#include <hip/hip_bf16.h>

typedef __bf16 bf16;
typedef __bf16 bf16x8 __attribute__((ext_vector_type(8)));
typedef __bf16 bf16x4 __attribute__((ext_vector_type(4)));
typedef __bf16 bf16x2 __attribute__((ext_vector_type(2)));
typedef float f32x4 __attribute__((ext_vector_type(4)));

#define BATCH 32
#define N_ID 1024
#define L_IN 512

static const long ACT_E = (long)BATCH * N_ID * L_IN;   // 16,777,216
static const long S_NL  = (long)N_ID * L_IN;           // 524288
static const long S_TT  = (long)N_ID * N_ID;           // 1048576

__device__ __forceinline__ void gload16(const bf16* g, bf16* l)
{
    __builtin_amdgcn_global_load_lds((__attribute__((address_space(1))) void*)g,
                                     (__attribute__((address_space(3))) void*)l, 16, 0, 0);
}

// ---------------------------------------------------------------------------
// 128x128 BK=32 triple-buffered counted-vmcnt NT GEMM (3 blocks/CU).
// C[m,n] = sum_k A[m,k]*B[n,k]; strides lda/ldb/ldc decoupled.
// EPI: 1 bf16=acc+biasRow[m]; 3 bf16=acc;
//      6 bf16=exp2(acc*scale + vpre[z*sBR+cc]); atomic rowsum -> biasRow[z*sBR+rr]
//      7 bf16=acc/Rsum[z*sBR+rr]+ResBF16+biasCol[cc]   (time/cross PV)
//      8 bf16=acc/Rsum[z*sBR+cc]*scal2[0]+scal2[1]     (space PV)
// ---------------------------------------------------------------------------
#define VM8 asm volatile("s_waitcnt vmcnt(8)" ::: "memory")
#define VM4 asm volatile("s_waitcnt vmcnt(4)" ::: "memory")
#define VM0 asm volatile("s_waitcnt vmcnt(0)" ::: "memory")
#define BAR __builtin_amdgcn_s_barrier()

#define COMPUTE(CIDX) \
    { \
      const bf16* pa = ldsb + (CIDX) * 8192; \
      const bf16* pb = pa + 4096; \
      bf16x8 af[4], bfv[4]; \
_Pragma("unroll") \
      for (int i = 0; i < 4; ++i) \
        af[i] = *(const bf16x8*)(pa + (wm * 64 + i * 16 + fr) * 32 + slotk); \
_Pragma("unroll") \
      for (int j = 0; j < 4; ++j) \
        bfv[j] = *(const bf16x8*)(pb + (wn * 64 + j * 16 + fr) * 32 + slotk); \
      __builtin_amdgcn_s_setprio(1); \
_Pragma("unroll") \
      for (int i = 0; i < 4; ++i) \
_Pragma("unroll") \
        for (int j = 0; j < 4; ++j) \
          acc[i][j] = __builtin_amdgcn_mfma_f32_16x16x32_bf16(af[i], bfv[j], acc[i][j], 0, 0, 0); \
      __builtin_amdgcn_s_setprio(0); \
    }

#define STAGE(CIDX, KT) { stg(ldsb + (CIDX) * 8192, Ab, lda, m0, KT); \
                          stg(ldsb + (CIDX) * 8192 + 4096, Bb, ldb, n0, KT); }

template<int EPI>
__global__ __launch_bounds__(256, 3)
void gemm3(const bf16* __restrict__ A, const bf16* __restrict__ Bm, void* __restrict__ Cout,
           const float* __restrict__ biasCol, const float* __restrict__ biasRow,
           const void* __restrict__ Res, const float* __restrict__ scal2,
           float scale, int K,
           long lda, long ldb, long ldc,
           long sA, long sB, long sC, long sRes, long sBR,
           unsigned gy, unsigned gxy, unsigned nwg)
{
    __shared__ __align__(16) bf16 ldsbuf[3 * 2 * 4096];   // 48 KB
    bf16* ldsb = ldsbuf;

    unsigned id = blockIdx.x;
    {
        const unsigned q = nwg >> 3, r = nwg & 7;
        const unsigned xcd = id & 7, off = id >> 3;
        id = (xcd < r ? xcd * (q + 1) : r * (q + 1) + (xcd - r) * q) + off;
    }
    const unsigned bz = id / gxy;
    const unsigned rem = id - bz * gxy;
    const unsigned bx = rem / gy;        // M-tile: slow (A-panel reuse)
    const unsigned by = rem - bx * gy;   // N-tile: fastest

    const int t = threadIdx.x;
    const int w = t >> 6;
    const int lane = t & 63;
    const int fr = lane & 15;
    const int kg = lane >> 4;
    const int wm = w >> 1, wn = w & 1;
    const long z = bz;
    const long m0 = (long)bx * 128;
    const long n0 = (long)by * 128;
    const bf16* Ab = A + z * sA;
    const bf16* Bb = Bm + z * sB;

    const int srow = w * 16 + (lane >> 2);
    const int gc = (lane & 3) ^ ((lane >> 3) & 3);
    const int slotk = (kg ^ ((fr >> 1) & 3)) * 8;

    auto stg = [&](bf16* dst, const bf16* base, long ld, long rc0, int kt) {
#pragma unroll
        for (int r = 0; r < 2; ++r) {
            const int row = r * 64 + srow;
            const bf16* src = base + (rc0 + row) * ld + kt * 32 + gc * 8;
            gload16(src, dst + row * 32 + (lane & 3) * 8);
        }
    };

    f32x4 acc[4][4] = {};

    const int NT = K >> 5;
    STAGE(0, 0); STAGE(1, 1); STAGE(2, 2);

    int c = 0;
    for (int kt = 0; kt < NT - 2; ++kt) {
        VM8; BAR;
        COMPUTE(c);
        BAR;
        if (kt + 3 < NT) STAGE(c, kt + 3);
        c = (c == 2) ? 0 : c + 1;
    }
    VM4; BAR;
    COMPUTE(c);
    BAR;
    c = (c == 2) ? 0 : c + 1;
    VM0; BAR;
    COMPUTE(c);

    float e0 = 0.f, e1 = 0.f;
    if constexpr (EPI == 8) { e0 = scal2[0]; e1 = scal2[1]; }

    float rs[16];
    if constexpr (EPI == 6) {
#pragma unroll
        for (int vv = 0; vv < 16; ++vv) rs[vv] = 0.f;
    }

#pragma unroll
    for (int i = 0; i < 4; ++i) {
        const long rb = m0 + wm * 64 + i * 16 + kg * 4;
        float rin[4];
        if constexpr (EPI == 7) {
#pragma unroll
            for (int r = 0; r < 4; ++r) rin[r] = 1.f / biasRow[z * sBR + rb + r];
        }
#pragma unroll
        for (int j = 0; j < 4; ++j) {
            const long cc = n0 + wn * 64 + j * 16 + fr;
            float cinv = 0.f, vj = 0.f;
            if constexpr (EPI == 8) cinv = 1.f / biasCol[z * sBR + cc];
            if constexpr (EPI == 6) vj = biasCol[z * sBR + cc];
#pragma unroll
            for (int r = 0; r < 4; ++r) {
                const long rr = rb + r;
                const float v = acc[i][j][r];
                const long idx = z * sC + rr * ldc + cc;
                if constexpr (EPI == 1)      ((bf16*)Cout)[idx] = (bf16)(v + biasRow[rr]);
                else if constexpr (EPI == 3) ((bf16*)Cout)[idx] = (bf16)v;
                else if constexpr (EPI == 6) {
                    const float e = __builtin_amdgcn_exp2f(v * scale + vj);
                    ((bf16*)Cout)[idx] = (bf16)e;
                    rs[i * 4 + r] += e;
                }
                else if constexpr (EPI == 7) ((bf16*)Cout)[idx] =
                    (bf16)(v * rin[r]
                           + (float)((const bf16*)Res)[z * sRes + rr * ldc + cc] + biasCol[cc]);
                else /* 8 */                 ((bf16*)Cout)[idx] = (bf16)(v * cinv * e0 + e1);
            }
        }
    }

    if constexpr (EPI == 6) {
#pragma unroll
        for (int vv = 0; vv < 16; ++vv) {
            rs[vv] += __shfl_xor(rs[vv], 1);
            rs[vv] += __shfl_xor(rs[vv], 2);
            rs[vv] += __shfl_xor(rs[vv], 4);
            rs[vv] += __shfl_xor(rs[vv], 8);
        }
        if (fr == 0) {
            float* Rs = (float*)biasRow + z * sBR;
#pragma unroll
            for (int i = 0; i < 4; ++i)
#pragma unroll
                for (int r = 0; r < 4; ++r) {
                    const long rr = m0 + wm * 64 + i * 16 + kg * 4 + r;
                    atomicAdd(Rs + rr, rs[i * 4 + r]);
                }
        }
    }
}

// ---------------------------------------------------------------------------
template<int OUTBF>
__global__ __launch_bounds__(128)
void ln_rows(const bf16* __restrict__ X, const float* __restrict__ g,
             const float* __restrict__ bta, void* __restrict__ out)
{
    const long row = blockIdx.x;
    const int t = threadIdx.x;
    bf16x4 b4 = *(const bf16x4*)(X + row * 512 + t * 4);
    float v[4] = { (float)b4[0], (float)b4[1], (float)b4[2], (float)b4[3] };
    float s1 = v[0] + v[1] + v[2] + v[3];
    float s2 = v[0]*v[0] + v[1]*v[1] + v[2]*v[2] + v[3]*v[3];
#pragma unroll
    for (int o = 32; o > 0; o >>= 1) { s1 += __shfl_xor(s1, o); s2 += __shfl_xor(s2, o); }
    __shared__ float r1[2], r2[2];
    const int w = t >> 6, l = t & 63;
    if (l == 0) { r1[w] = s1; r2[w] = s2; }
    __syncthreads();
    s1 = r1[0] + r1[1];
    s2 = r2[0] + r2[1];
    const float mean = s1 * (1.f / 512.f);
    const float var  = s2 * (1.f / 512.f) - mean * mean;
    const float rstd = rsqrtf(var + 1e-5f);
    const int c = t * 4;
    if constexpr (OUTBF) {
        bf16x4 o4;
#pragma unroll
        for (int k = 0; k < 4; ++k) o4[k] = (bf16)((v[k] - mean) * rstd * g[c + k] + bta[c + k]);
        *(bf16x4*)((bf16*)out + row * 512 + c) = o4;
    } else {
        f32x4 o4;
#pragma unroll
        for (int k = 0; k < 4; ++k) o4[k] = (v[k] - mean) * rstd * g[c + k] + bta[c + k];
        *(f32x4*)((float*)out + row * 512 + c) = o4;
    }
}

// ---------------------------------------------------------------------------
__global__ __launch_bounds__(256)
void transpose_cvt(const float* __restrict__ x, bf16* __restrict__ Xb, bf16* __restrict__ xt)
{
    __shared__ bf16 tile[32][33];
    const int b = blockIdx.z;
    const int n0 = blockIdx.x * 32, l0 = blockIdx.y * 32;
    const long base = (long)b * N_ID * L_IN;
    const int tx = threadIdx.x, ty = threadIdx.y;
#pragma unroll
    for (int i = ty; i < 32; i += 8) {
        const long idx = base + (long)(n0 + i) * L_IN + l0 + tx;
        const bf16 s = (bf16)x[idx];
        Xb[idx] = s;
        tile[i][tx] = s;
    }
    __syncthreads();
#pragma unroll
    for (int i = ty; i < 32; i += 8)
        xt[base + (long)(l0 + i) * N_ID + n0 + tx] = tile[tx][i];
}

// N x N f32 -> transposed bf16 (two jobs via z)
template<int N>
__global__ __launch_bounds__(256)
void transpose_mat(const float* __restrict__ a, const float* __restrict__ b,
                   bf16* __restrict__ da, bf16* __restrict__ db)
{
    __shared__ bf16 tile[32][33];
    const float* src = blockIdx.z ? b : a;
    bf16* dst = blockIdx.z ? db : da;
    const int c0 = blockIdx.x * 32, r0 = blockIdx.y * 32;
    const int tx = threadIdx.x, ty = threadIdx.y;
#pragma unroll
    for (int i = ty; i < 32; i += 8)
        tile[i][tx] = (bf16)src[(long)(r0 + i) * N + c0 + tx];
    __syncthreads();
#pragma unroll
    for (int i = ty; i < 32; i += 8)
        dst[(long)(c0 + i) * N + r0 + tx] = tile[tx][i];
}

__global__ void cvt_one(const float* __restrict__ s, bf16* __restrict__ d, int n)
{
    const int i = (blockIdx.x * 256 + threadIdx.x) * 4;
    if (i < n) {
        f32x4 v = *(const f32x4*)(s + i);
        bf16x4 o; o[0] = (bf16)v[0]; o[1] = (bf16)v[1]; o[2] = (bf16)v[2]; o[3] = (bf16)v[3];
        *(bf16x4*)(d + i) = o;
    }
}

__global__ void wo_sum2(const float* __restrict__ a, const float* __restrict__ b,
                        bf16* __restrict__ da, bf16* __restrict__ db)
{
    const int i = blockIdx.x * 256 + threadIdx.x;
    const float* src = blockIdx.y ? b : a;
    bf16* dst = blockIdx.y ? db : da;
    const float* p = src + (long)i * 8;
    float s = 0.f;
#pragma unroll
    for (int h = 0; h < 8; ++h) s += p[h];
    dst[i] = (bf16)s;
}

// two biasfolds batched via y: out[o] = bo[o] + sum_l Ws[o,l]*bv[l]
__global__ __launch_bounds__(64)
void biasfold2(const bf16* __restrict__ WsA, const float* __restrict__ bvA, const float* __restrict__ boA, float* __restrict__ outA,
               const bf16* __restrict__ WsB, const float* __restrict__ bvB, const float* __restrict__ boB, float* __restrict__ outB)
{
    const bf16* Ws = blockIdx.y ? WsB : WsA;
    const float* bv = blockIdx.y ? bvB : bvA;
    const float* bo = blockIdx.y ? boB : boA;
    float* out = blockIdx.y ? outB : outA;
    const int o = blockIdx.x;
    float s = 0.f;
    for (int l = threadIdx.x; l < 512; l += 64)
        s += (float)Ws[(long)o * 512 + l] * bv[l];
#pragma unroll
    for (int off = 32; off > 0; off >>= 1) s += __shfl_xor(s, off);
    if (threadIdx.x == 0) out[o] = bo[o] + s;
}

// vbar folds + scal (jobs via y): vbar[o] = sum_a WkTr[o,a]*bq[a]
__global__ __launch_bounds__(64)
void vbarfold(const bf16* WkTrT, const float* tbq, float* vbarT,
              const bf16* WkTrC, const float* cbq, float* vbarC,
              const bf16* sWkTr, const float* sbq, float* vbarS,
              const float* sW1, const float* sb1, float* scal)
{
    const int o = blockIdx.x;
    const int y = blockIdx.y;
    if (y == 3) {
        if (o == 0 && threadIdx.x == 0) {
            float s = 0.f;
            for (int h = 0; h < 8; ++h) s += sW1[h];
            scal[0] = s; scal[1] = sb1[0];
        }
        return;
    }
    const bf16* W; const float* b; float* out; int D;
    if (y == 0)      { if (o >= 512) return; W = WkTrT; b = tbq; out = vbarT; D = 512; }
    else if (y == 1) { if (o >= 512) return; W = WkTrC; b = cbq; out = vbarC; D = 512; }
    else             { W = sWkTr; b = sbq; out = vbarS; D = 1024; }
    float s = 0.f;
    for (int a = threadIdx.x; a < D; a += 64)
        s += (float)W[(long)o * D + a] * b[a];
#pragma unroll
    for (int off = 32; off > 0; off >>= 1) s += __shfl_xor(s, off);
    if (threadIdx.x == 0) out[o] = s;
}

// vpre[row] = scale2 * sum_d Src[row*D+d]*vbar[d]   (one wave per row)
template<int D>
__global__ __launch_bounds__(256)
void vrow(const bf16* __restrict__ Src, const float* __restrict__ vbar,
          float* __restrict__ out, float scale2)
{
    const long row = (long)blockIdx.x * 4 + (threadIdx.x >> 6);
    const int lane = threadIdx.x & 63;
    const bf16* r = Src + row * D;
    float s = 0.f;
#pragma unroll
    for (int u = 0; u < D / 512; ++u) {
        bf16x8 xv = *(const bf16x8*)(r + u * 512 + lane * 8);
        const float* vb = vbar + u * 512 + lane * 8;
#pragma unroll
        for (int e = 0; e < 8; ++e) s += (float)xv[e] * vb[e];
    }
#pragma unroll
    for (int o = 32; o > 0; o >>= 1) s += __shfl_xor(s, o);
    if (lane == 0) out[row] = s * scale2;
}

// ---------------------------------------------------------------------------
static void launch_gemm(int epi, const bf16* A, const bf16* B, void* C,
                        const float* bc, const float* br, const void* res, const float* sc2,
                        float scale, int M, int N, int K,
                        long lda, long ldb, long ldc,
                        long sA, long sB, long sC, long sRes, long sBR,
                        int batches, hipStream_t st)
{
    const unsigned gx = M / 128, gy = N / 128;
    const unsigned gxy = gx * gy, nwg = gxy * (unsigned)batches;
    dim3 g(nwg), blk(256);
    switch (epi) {
    case 1: gemm3<1><<<g, blk, 0, st>>>(A, B, C, bc, br, res, sc2, scale, K, lda, ldb, ldc, sA, sB, sC, sRes, sBR, gy, gxy, nwg); break;
    case 3: gemm3<3><<<g, blk, 0, st>>>(A, B, C, bc, br, res, sc2, scale, K, lda, ldb, ldc, sA, sB, sC, sRes, sBR, gy, gxy, nwg); break;
    case 6: gemm3<6><<<g, blk, 0, st>>>(A, B, C, bc, br, res, sc2, scale, K, lda, ldb, ldc, sA, sB, sC, sRes, sBR, gy, gxy, nwg); break;
    case 7: gemm3<7><<<g, blk, 0, st>>>(A, B, C, bc, br, res, sc2, scale, K, lda, ldb, ldc, sA, sB, sC, sRes, sBR, gy, gxy, nwg); break;
    default: gemm3<8><<<g, blk, 0, st>>>(A, B, C, bc, br, res, sc2, scale, K, lda, ldb, ldc, sA, sB, sC, sRes, sBR, gy, gxy, nwg); break;
    }
}

extern "C" void kernel_launch(void* const* d_in, const int* in_sizes, int n_in,
                              void* d_out, int out_size, void* d_ws, size_t ws_size,
                              hipStream_t stream)
{
    (void)in_sizes; (void)n_in; (void)out_size;

    const float* x   = (const float*)d_in[0];
    const float* tWq = (const float*)d_in[1];  const float* tbq = (const float*)d_in[2];
    const float* tWk = (const float*)d_in[3];  const float* tbk = (const float*)d_in[4];
    const float* tWv = (const float*)d_in[5];  const float* tbv = (const float*)d_in[6];
    const float* tWo = (const float*)d_in[7];  const float* tbo = (const float*)d_in[8];
    const float* tg  = (const float*)d_in[9];  const float* tb  = (const float*)d_in[10];
    const float* cWq = (const float*)d_in[11]; const float* cbq = (const float*)d_in[12];
    const float* cWk = (const float*)d_in[13]; const float* cbk = (const float*)d_in[14];
    const float* cWv = (const float*)d_in[15]; const float* cbv = (const float*)d_in[16];
    const float* cWo = (const float*)d_in[17]; const float* cbo = (const float*)d_in[18];
    const float* cg  = (const float*)d_in[19]; const float* cb  = (const float*)d_in[20];
    const float* sWq = (const float*)d_in[21]; const float* sbq = (const float*)d_in[22];
    const float* sWk = (const float*)d_in[23]; const float* sbk = (const float*)d_in[24];
    const float* sWv = (const float*)d_in[25]; const float* sbv = (const float*)d_in[26];
    const float* sW1 = (const float*)d_in[27]; const float* sb1 = (const float*)d_in[28];
    (void)tbk; (void)cbk; (void)sbk;   // key biases: row-constant terms cancel in softmax

    char* p = (char*)d_ws;
    auto alloc = [&](size_t bytes) -> char* {
        char* r = p; p += (bytes + 255) & ~(size_t)255; return r;
    };

    // A-chain (contiguous, stride 262144 elems) for batched z=4 prep GEMM
    bf16* WsT   = (bf16*)alloc(262144 * 2);
    bf16* WsC   = (bf16*)alloc(262144 * 2);
    bf16* WkTrT = (bf16*)alloc(262144 * 2);
    bf16* WkTrC = (bf16*)alloc(262144 * 2);
    // B-chain
    bf16* WvTrT = (bf16*)alloc(262144 * 2);
    bf16* WvTrC = (bf16*)alloc(262144 * 2);
    bf16* WqTrT = (bf16*)alloc(262144 * 2);
    bf16* WqTrC = (bf16*)alloc(262144 * 2);
    // C-chain
    bf16* WvWT  = (bf16*)alloc(262144 * 2);
    bf16* WvWC  = (bf16*)alloc(262144 * 2);
    bf16* MTt   = (bf16*)alloc(262144 * 2);
    bf16* MTc   = (bf16*)alloc(262144 * 2);
    // space (1024^2)
    bf16* sWqTr = (bf16*)alloc(1048576 * 2);
    bf16* sWkTr = (bf16*)alloc(1048576 * 2);
    bf16* MTs   = (bf16*)alloc(1048576 * 2);
    bf16* WvS   = (bf16*)alloc(1048576 * 2);
    float* scal  = (float*)alloc(256);
    float* biasT = (float*)alloc(512 * 4);
    float* biasC = (float*)alloc(512 * 4);
    float* vbarT = (float*)alloc(512 * 4);
    float* vbarC = (float*)alloc(512 * 4);
    float* vbarS = (float*)alloc(1024 * 4);

    const size_t ACT_B = (size_t)ACT_E * 2;
    bf16* bufG = (bf16*)alloc(ACT_B);   // G = A·M (score operand)
    bf16* Xb   = (bf16*)alloc(ACT_B);   // reused as SO after stage T
    bf16* TO   = (bf16*)alloc(ACT_B);
    bf16* xt   = (bf16*)alloc(ACT_B);
    bf16* bufV = (bf16*)alloc(ACT_B);
    bf16* PL   = (bf16*)alloc(ACT_B);
    float* vpre = (float*)alloc(BATCH * 1024 * 4);
    float* Rbuf = (float*)alloc(BATCH * 1024 * 4);

    size_t used = (size_t)(p - (char*)d_ws);
    int CB = 32;
    while (CB > 1 && used + (size_t)CB * 2097152ULL + 4096 > ws_size) CB >>= 1;
    bf16* Sbuf = (bf16*)alloc((size_t)CB * 2097152ULL);
    bf16* Pbuf = Sbuf;

    const float L2E = 1.4426950408889634f;
    const float rsc_t2 = 0.08838834764831845f * L2E;
    const float rsc_s2 = 0.125f * L2E;

    // ---- prep ----
    transpose_mat<512><<<dim3(16, 16, 2), dim3(32, 8), 0, stream>>>(tWv, cWv, WvTrT, WvTrC);
    transpose_mat<512><<<dim3(16, 16, 2), dim3(32, 8), 0, stream>>>(tWq, cWq, WqTrT, WqTrC);
    transpose_mat<512><<<dim3(16, 16, 2), dim3(32, 8), 0, stream>>>(tWk, cWk, WkTrT, WkTrC);
    transpose_mat<1024><<<dim3(32, 32, 2), dim3(32, 8), 0, stream>>>(sWq, sWk, sWqTr, sWkTr);
    cvt_one<<<dim3(1024), dim3(256), 0, stream>>>(sWv, WvS, 1048576);
    wo_sum2<<<dim3(1024, 2), dim3(256), 0, stream>>>(tWo, cWo, WsT, WsC);
    biasfold2<<<dim3(512, 2), dim3(64), 0, stream>>>(WsT, tbv, tbo, biasT, WsC, cbv, cbo, biasC);
    vbarfold<<<dim3(1024, 4), dim3(64), 0, stream>>>(WkTrT, tbq, vbarT, WkTrC, cbq, vbarC,
                                                     sWkTr, sbq, vbarS, sW1, sb1, scal);
    // batched z=4: {WvWT, WvWC, MTt, MTc} = NT(A-chain, B-chain)
    launch_gemm(3, WsT, WvTrT, WvWT, nullptr, nullptr, nullptr, nullptr, 0.f,
                512, 512, 512, 512, 512, 512, 262144, 262144, 262144, 0, 0, 4, stream);
    // MTs = NT(sWkTr, sWqTr)
    launch_gemm(3, sWkTr, sWqTr, MTs, nullptr, nullptr, nullptr, nullptr, 0.f,
                1024, 1024, 1024, 1024, 1024, 1024, 0, 0, 0, 0, 0, 1, stream);
    transpose_cvt<<<dim3(32, 16, BATCH), dim3(32, 8), 0, stream>>>(x, Xb, xt);

    // time/cross attention: S=exp2(G·K^T*scale + vpre[col]) [+atomic rowsum]
    // -> preLN = (P@VW^T)/Rsum + Res + bias'
    auto attn_tc = [&](const bf16* Kb, const bf16* ResP, const float* biasP) {
        for (int c0 = 0; c0 < BATCH; c0 += CB) {
            const long off = (long)c0 * S_NL;
            hipMemsetAsync(Rbuf, 0, (size_t)CB * 1024 * 4, stream);
            launch_gemm(6, bufG + off, Kb + off, Sbuf, vpre + (long)c0 * 1024, Rbuf, nullptr, nullptr, rsc_t2,
                        1024, 1024, 512, 512, 512, 1024, S_NL, S_NL, S_TT, 0, 1024, CB, stream);
            launch_gemm(7, Pbuf, bufV + off, PL + off, biasP, Rbuf, ResP + off, nullptr, 0.f,
                        1024, 512, 1024, 1024, 1024, 512, S_TT, S_NL, S_NL, S_NL, 1024, CB, stream);
        }
    };

    // ==== Stage T (time de_att) ====
    launch_gemm(3, Xb, MTt, bufG, nullptr, nullptr, nullptr, nullptr, 0.f,
                32768, 512, 512, 512, 512, 512, 0, 0, 0, 0, 0, 1, stream);
    launch_gemm(3, WvWT, Xb, bufV, nullptr, nullptr, nullptr, nullptr, 0.f,
                512, 1024, 512, 512, 512, 1024, 0, S_NL, S_NL, 0, 0, BATCH, stream);
    vrow<512><<<dim3(8192), dim3(256), 0, stream>>>(Xb, vbarT, vpre, rsc_t2);
    attn_tc(Xb, Xb, biasT);
    ln_rows<1><<<dim3(32768), dim3(128), 0, stream>>>(PL, tg, tb, TO);

    // ==== Stage S (space attention) ====
    bf16* SOp = Xb;   // Xb dead after stage T -> space_out
    launch_gemm(3, xt, MTs, bufG, nullptr, nullptr, nullptr, nullptr, 0.f,
                16384, 1024, 1024, 1024, 1024, 1024, 0, 0, 0, 0, 0, 1, stream);
    launch_gemm(1, WvS, xt, bufV, nullptr, sbv, nullptr, nullptr, 0.f,
                1024, 512, 1024, 1024, 1024, 512, 0, S_NL, S_NL, 0, 0, BATCH, stream);
    vrow<1024><<<dim3(4096), dim3(256), 0, stream>>>(xt, vbarS, vpre, rsc_s2);
    for (int c0 = 0; c0 < BATCH; c0 += CB) {
        const long off = (long)c0 * S_NL;
        hipMemsetAsync(Rbuf, 0, (size_t)CB * 512 * 4, stream);
        launch_gemm(6, bufG + off, xt + off, Sbuf, vpre + (long)c0 * 512, Rbuf, nullptr, nullptr, rsc_s2,
                    512, 512, 1024, 1024, 1024, 512, S_NL, S_NL, (long)L_IN * L_IN, 0, 512, CB, stream);
        launch_gemm(8, bufV + off, Pbuf, SOp + off, Rbuf, nullptr, nullptr, scal, 0.f,
                    1024, 512, 512, 512, 512, 512, S_NL, (long)L_IN * L_IN, S_NL, 0, 512, CB, stream);
    }

    // ==== Stage C (cross de_att) ====
    launch_gemm(3, Xb, MTc, bufG, nullptr, nullptr, nullptr, nullptr, 0.f,
                32768, 512, 512, 512, 512, 512, 0, 0, 0, 0, 0, 1, stream);
    launch_gemm(3, WvWC, TO, bufV, nullptr, nullptr, nullptr, nullptr, 0.f,
                512, 1024, 512, 512, 512, 1024, 0, S_NL, S_NL, 0, 0, BATCH, stream);
    vrow<512><<<dim3(8192), dim3(256), 0, stream>>>(TO, vbarC, vpre, rsc_t2);
    attn_tc(TO, TO, biasC);
    ln_rows<0><<<dim3(32768), dim3(128), 0, stream>>>(PL, cg, cb, d_out);
}